// Round 18
// baseline (14444.641 us; speedup 1.0000x reference)
//
#include <hip/hip_runtime.h>
#include <math.h>

// Problem constants (fixed by setup_inputs)
#define BB  64      // batch
#define TT  512     // seq len
#define HH  512     // hidden
#define RR  1024    // decode rows = B*S
#define HOR 64      // horizon

// encoder geometry
#define EWG 128     // encoder WGs (each owns 4 hcols = 16 gate-rows/matrix)
#define ETH 512     // threads (8 waves)
#define DWG 256     // decoder WGs

typedef unsigned short ushort;
typedef unsigned long long u64;
typedef __attribute__((ext_vector_type(8))) short bf16x8;     // 8 bf16 (4 VGPRs)
typedef __attribute__((ext_vector_type(8))) unsigned short ushort8;
typedef __attribute__((ext_vector_type(4))) float f32x4;

// Persistent state in device globals (re-initialized every launch)
__device__ float g_c0[BB][HH];
__device__ float g_c1[BB][HH];
__device__ float g_C0[RR][HH];
__device__ float g_C1[RR][HH];
__device__ float g_u[2][RR];       // u double-buffer: g_u[d&1] feeds step d
// encoder h state, split-bf16 (hi + lo residual)
__device__ ushort Eh0h[2][BB][HH], Eh0l[2][BB][HH];
__device__ ushort Eh1h[2][BB][HH], Eh1l[2][BB][HH];
// split-bf16 decoder state (hi + lo residual; GEMM A operands)
__device__ ushort H0h[2][RR][HH], H0l[2][RR][HH];
__device__ ushort H1h[2][RR][HH], H1l[2][RR][HH];
// split-bf16 weights (prep kernel, once per launch)
__device__ ushort Whh0h[4 * HH][HH], Whh0l[4 * HH][HH];
__device__ ushort Wih1h[4 * HH][HH], Wih1l[4 * HH][HH];
__device__ ushort Whh1h[4 * HH][HH], Whh1l[4 * HH][HH];

__device__ __forceinline__ float sigf(float v) { return 1.0f / (1.0f + expf(-v)); }

__device__ __forceinline__ float cellupd(float iv, float fv, float gv, float ov, float& c) {
  c = sigf(fv) * c + sigf(iv) * tanhf(gv);
  return sigf(ov) * tanhf(c);
}

// bf16 RNE helpers
__device__ __forceinline__ ushort f2bf(float x) {
  unsigned u = __float_as_uint(x);
  unsigned r = u + 0x7FFFu + ((u >> 16) & 1u);
  return (ushort)(r >> 16);
}
__device__ __forceinline__ float bf2f(ushort h) {
  return __uint_as_float(((unsigned)h) << 16);
}

// ---- Master-flag fence-hoisted barrier ----
// Arrival: ONE wbl2 fence + relaxed slot store (own cacheline). WG0's lanes
// poll the N slots in parallel; WG0 then sets ONE flag; all other WGs poll
// only that read-shared flag line (poll traffic / ~N vs all-poll-all).
// ONE inv fence after release. SAFETY (R2/R4 hangs): every grid using this
// must have >=2x co-residency slack (enc: 114KB LDS -> 1 WG/CU, 128 vs 256;
// dec: 57KB -> 2 WG/CU, 256 vs 512).
template <int NWGS>
__device__ __forceinline__ void gbar(unsigned* slots, unsigned* flag, unsigned p) {
  __syncthreads();
  if (threadIdx.x == 0) {
    __threadfence();  // wbl2: publish this WG's writes
    __hip_atomic_store(slots + blockIdx.x * 32, p, __ATOMIC_RELAXED,
                       __HIP_MEMORY_SCOPE_AGENT);
  }
  if (blockIdx.x == 0) {
    if (threadIdx.x < NWGS) {
      while (__hip_atomic_load(slots + threadIdx.x * 32, __ATOMIC_RELAXED,
                               __HIP_MEMORY_SCOPE_AGENT) < p)
        __builtin_amdgcn_s_sleep(1);
    }
    __syncthreads();
    if (threadIdx.x == 0) {
      __hip_atomic_store(flag, p, __ATOMIC_RELAXED, __HIP_MEMORY_SCOPE_AGENT);
      __threadfence();  // inv: fresh reads of peers' state
    }
  } else {
    if (threadIdx.x == 0) {
      while (__hip_atomic_load(flag, __ATOMIC_RELAXED,
                               __HIP_MEMORY_SCOPE_AGENT) < p)
        __builtin_amdgcn_s_sleep(2);
      __threadfence();  // inv
    }
  }
  __syncthreads();
}

// ======================= PREP: split weights to bf16 hi/lo =======================
__global__ __launch_bounds__(512) void prep_split(
    const float* __restrict__ whh0, const float* __restrict__ wih1,
    const float* __restrict__ whh1) {
  const int i = blockIdx.x * 512 + threadIdx.x;  // grid 2048 -> 1M elements
  float a = whh0[i];
  ushort h = f2bf(a);
  (&Whh0h[0][0])[i] = h;
  (&Whh0l[0][0])[i] = f2bf(a - bf2f(h));
  a = wih1[i];
  h = f2bf(a);
  (&Wih1h[0][0])[i] = h;
  (&Wih1l[0][0])[i] = f2bf(a - bf2f(h));
  a = whh1[i];
  h = f2bf(a);
  (&Whh1h[0][0])[i] = h;
  (&Whh1l[0][0])[i] = f2bf(a - bf2f(h));
}

// swizzled ushort offset within a 16x512 weight plane for (row jl, chunk ck)
__device__ __forceinline__ int wswz(int jl, int ck) {
  return jl * 512 + (((ck & 56) | ((ck ^ jl) & 7)) << 3);
}

#define GST 20  // gate-exchange row stride (floats); 80B = 16B-aligned

// ======================= ENCODER (persistent, split-bf16 MFMA; R17 body) =======
__global__ __launch_bounds__(ETH, 2) void enc_kernel(
    const float* __restrict__ x, const float* __restrict__ init_input,
    const float* __restrict__ w_ih0, const float* __restrict__ b0,
    const float* __restrict__ b1, unsigned* ws) {
  const int wg = blockIdx.x;
  const int tid = threadIdx.x;
  const int hcol0 = wg * 4;
  unsigned* eslots = ws;               // 128 slots x 32 stride
  unsigned* eflag = ws + 4096;

  __shared__ __align__(16) ushort sW[6][16 * 512];  // [mat*2+half]
  __shared__ float s_gb0[64 * GST];   // [b][hl*4+gate] (stride-padded)
  __shared__ float s_gb1a[64 * GST];
  __shared__ float s_gb1b[64 * GST];
  __shared__ float s_wih0[16], s_b0[16], s_b1[16];

  // ---- load resident weight slices (once): 6 planes x 1024 chunks ----
  for (int i = tid; i < 6 * 1024; i += ETH) {
    const int plane = i >> 10, c = i & 1023;
    const int row = c >> 6, ck = c & 63;
    const int jsrc = (row >> 2) * HH + hcol0 + (row & 3);
    const ushort* src;
    switch (plane) {
      case 0: src = &Whh0h[0][0]; break;
      case 1: src = &Whh0l[0][0]; break;
      case 2: src = &Wih1h[0][0]; break;
      case 3: src = &Wih1l[0][0]; break;
      case 4: src = &Whh1h[0][0]; break;
      default: src = &Whh1l[0][0]; break;
    }
    *(ushort8*)&sW[plane][wswz(row, ck)] =
        *(const ushort8*)&src[jsrc * HH + ck * 8];
  }
  if (tid < 16) {  // jl = gate*4 + hl
    const int jsrc = (tid >> 2) * HH + hcol0 + (tid & 3);
    s_wih0[tid] = w_ih0[jsrc];
    s_b0[tid] = b0[jsrc];
    s_b1[tid] = b1[jsrc];
  }
  {  // zero-init h state (published by barrier's wbl2 fence)
    const int gid = wg * ETH + tid;  // 65536 threads; 8192 ushort8 quads
    if (gid < 8192) {
      const int o = gid * 8;
      *(ushort8*)&(&Eh0h[0][0][0])[o] = (ushort8)(0);
      *(ushort8*)&(&Eh0l[0][0][0])[o] = (ushort8)(0);
      *(ushort8*)&(&Eh1h[0][0][0])[o] = (ushort8)(0);
      *(ushort8*)&(&Eh1l[0][0][0])[o] = (ushort8)(0);
    }
    if (tid < 256) {  // own c slice (4 hcols x 64 b): self-write-self-read
      const int b = tid >> 2, hc = hcol0 + (tid & 3);
      g_c0[b][hc] = 0.f;
      g_c1[b][hc] = 0.f;
    }
  }
  unsigned p = 1;
  gbar<EWG>(eslots, eflag, p);

  const int lane = tid & 63, wv = tid >> 6;
  const int grp = wv >> 2;      // 0: h0 -> acc0+acc1a; 1: h1 -> acc1b
  const int mh = wv & 3;        // m-tile: batch rows mh*16..+15
  const int mr = lane & 15, kg = lane >> 4;
  const int arow = mh * 16 + mr;
  // cell indices
  const int cb = tid >> 2, chl = tid & 3;
  const int chcol = hcol0 + chl;

  for (int tk = 1; tk <= TT + 1; ++tk) {
    const int cur = (tk - 1) & 1, nxt = tk & 1;
    const bool do0 = (tk <= TT), do1 = (tk >= 2);

    f32x4 acc0 = {0.f, 0.f, 0.f, 0.f};
    f32x4 acc1 = {0.f, 0.f, 0.f, 0.f};
    bf16x8 abuf[16];

    if (grp == 0) {
      const ushort* __restrict__ hrow = &Eh0h[cur][arow][0];
      // ---- pass 1: hi fragments, bulk load then MFMA ----
#pragma unroll
      for (int i = 0; i < 16; ++i)
        abuf[i] = *(const bf16x8*)&hrow[(i >> 1) * 64 + (i & 1) * 32 + kg * 8];
#pragma unroll
      for (int i = 0; i < 16; ++i) {
        const int ck = (i >> 1) * 8 + (i & 1) * 4 + kg;
        if (do0) {
          const bf16x8 bh = *(const bf16x8*)&sW[0][wswz(mr, ck)];
          const bf16x8 bl = *(const bf16x8*)&sW[1][wswz(mr, ck)];
          acc0 = __builtin_amdgcn_mfma_f32_16x16x32_bf16(abuf[i], bh, acc0, 0, 0, 0);
          acc0 = __builtin_amdgcn_mfma_f32_16x16x32_bf16(abuf[i], bl, acc0, 0, 0, 0);
        }
        if (do1) {
          const bf16x8 bh = *(const bf16x8*)&sW[2][wswz(mr, ck)];
          const bf16x8 bl = *(const bf16x8*)&sW[3][wswz(mr, ck)];
          acc1 = __builtin_amdgcn_mfma_f32_16x16x32_bf16(abuf[i], bh, acc1, 0, 0, 0);
          acc1 = __builtin_amdgcn_mfma_f32_16x16x32_bf16(abuf[i], bl, acc1, 0, 0, 0);
        }
      }
      // ---- pass 2: lo fragments x hi weights ----
      const ushort* __restrict__ lrow = &Eh0l[cur][arow][0];
#pragma unroll
      for (int i = 0; i < 16; ++i)
        abuf[i] = *(const bf16x8*)&lrow[(i >> 1) * 64 + (i & 1) * 32 + kg * 8];
#pragma unroll
      for (int i = 0; i < 16; ++i) {
        const int ck = (i >> 1) * 8 + (i & 1) * 4 + kg;
        if (do0) {
          const bf16x8 bh = *(const bf16x8*)&sW[0][wswz(mr, ck)];
          acc0 = __builtin_amdgcn_mfma_f32_16x16x32_bf16(abuf[i], bh, acc0, 0, 0, 0);
        }
        if (do1) {
          const bf16x8 bh = *(const bf16x8*)&sW[2][wswz(mr, ck)];
          acc1 = __builtin_amdgcn_mfma_f32_16x16x32_bf16(abuf[i], bh, acc1, 0, 0, 0);
        }
      }
    } else if (do1) {
      const ushort* __restrict__ hrow = &Eh1h[nxt][arow][0];
#pragma unroll
      for (int i = 0; i < 16; ++i)
        abuf[i] = *(const bf16x8*)&hrow[(i >> 1) * 64 + (i & 1) * 32 + kg * 8];
#pragma unroll
      for (int i = 0; i < 16; ++i) {
        const int ck = (i >> 1) * 8 + (i & 1) * 4 + kg;
        const bf16x8 bh = *(const bf16x8*)&sW[4][wswz(mr, ck)];
        const bf16x8 bl = *(const bf16x8*)&sW[5][wswz(mr, ck)];
        acc1 = __builtin_amdgcn_mfma_f32_16x16x32_bf16(abuf[i], bh, acc1, 0, 0, 0);
        acc1 = __builtin_amdgcn_mfma_f32_16x16x32_bf16(abuf[i], bl, acc1, 0, 0, 0);
      }
      const ushort* __restrict__ lrow = &Eh1l[nxt][arow][0];
#pragma unroll
      for (int i = 0; i < 16; ++i)
        abuf[i] = *(const bf16x8*)&lrow[(i >> 1) * 64 + (i & 1) * 32 + kg * 8];
#pragma unroll
      for (int i = 0; i < 16; ++i) {
        const int ck = (i >> 1) * 8 + (i & 1) * 4 + kg;
        const bf16x8 bh = *(const bf16x8*)&sW[4][wswz(mr, ck)];
        acc1 = __builtin_amdgcn_mfma_f32_16x16x32_bf16(abuf[i], bh, acc1, 0, 0, 0);
      }
    }

    // ---- gate exchange: C row (batch) = mh*16 + kg*4 + r, col jl = mr ----
    {
      const int slot = (mr & 3) * 4 + (mr >> 2);  // [hl][gate]
#pragma unroll
      for (int r = 0; r < 4; ++r) {
        const int b = mh * 16 + kg * 4 + r;
        if (grp == 0) {
          if (do0) s_gb0[b * GST + slot] = acc0[r];
          if (do1) s_gb1a[b * GST + slot] = acc1[r];
        } else if (do1) {
          s_gb1b[b * GST + slot] = acc1[r];
        }
      }
    }
    __syncthreads();

    // ---- cell updates: thread -> (b = tid>>2, hl = tid&3), tid < 256 ----
    if (tid < 256) {
      if (do0) {  // cell0 -> h0^{tk}
        const float xv = x[cb * TT + (tk - 1)];
        const float4 gb = *(const float4*)&s_gb0[cb * GST + chl * 4];
        const float iv = gb.x + xv * s_wih0[chl] + s_b0[chl];
        const float fv = gb.y + xv * s_wih0[4 + chl] + s_b0[4 + chl];
        const float gv = gb.z + xv * s_wih0[8 + chl] + s_b0[8 + chl];
        const float ov = gb.w + xv * s_wih0[12 + chl] + s_b0[12 + chl];
        float c = g_c0[cb][chcol];
        const float h = cellupd(iv, fv, gv, ov, c);
        g_c0[cb][chcol] = c;
        const ushort hh = f2bf(h);
        Eh0h[nxt][cb][chcol] = hh;
        Eh0l[nxt][cb][chcol] = f2bf(h - bf2f(hh));
      }
      if (do1) {  // cell1 -> h1^{tk-1}
        const float4 ga = *(const float4*)&s_gb1a[cb * GST + chl * 4];
        const float4 gbb = *(const float4*)&s_gb1b[cb * GST + chl * 4];
        const float iv = ga.x + gbb.x + s_b1[chl];
        const float fv = ga.y + gbb.y + s_b1[4 + chl];
        const float gv = ga.z + gbb.z + s_b1[8 + chl];
        const float ov = ga.w + gbb.w + s_b1[12 + chl];
        float c = g_c1[cb][chcol];
        const float h = cellupd(iv, fv, gv, ov, c);
        g_c1[cb][chcol] = c;
        const ushort hh = f2bf(h);
        Eh1h[cur][cb][chcol] = hh;
        Eh1l[cur][cb][chcol] = f2bf(h - bf2f(hh));
      }
    }
    gbar<EWG>(eslots, eflag, ++p);
  }

  // ---- expand final states over n_samples: row r = b*16+s ----
  {
    {  // ushort8 slots: RR*HH/8 = 65536 == grid threads
      const int idx = wg * ETH + tid;
      const int r = idx >> 6, k8 = (idx & 63) * 8, b = r >> 4;
      *(ushort8*)&H0h[0][r][k8] = *(const ushort8*)&Eh0h[0][b][k8];
      *(ushort8*)&H0l[0][r][k8] = *(const ushort8*)&Eh0l[0][b][k8];
      *(ushort8*)&H1h[0][r][k8] = *(const ushort8*)&Eh1h[0][b][k8];
      *(ushort8*)&H1l[0][r][k8] = *(const ushort8*)&Eh1l[0][b][k8];
    }
    // C expansion: OWN hcols only (c is local to this WG)
    for (int i = tid; i < RR * 4; i += ETH) {
      const int r = i >> 2, hc = hcol0 + (i & 3), b = r >> 4;
      g_C0[r][hc] = g_c0[b][hc];
      g_C1[r][hc] = g_c1[b][hc];
    }
    const int gid = wg * ETH + tid;
    if (gid < RR) g_u[0][gid] = init_input[gid];
  }
}

// ======================= DECODER (persistent, split-bf16 MFMA GEMMs) ===========
// One launch replaces 128: 256 WGs x 512 thr loop d = 0..63 with a grid
// barrier after each phase (l0, l1). Inner bodies byte-identical to the
// R12-verified dec_l0/dec_l1. LDS ~57KB -> 2 WG/CU (2x slack for barrier).
__global__ __launch_bounds__(512, 2) void dec_all(
    const float* __restrict__ w_ih0, const float* __restrict__ b0,
    const float* __restrict__ b1, const float* __restrict__ w_out,
    const float* __restrict__ b_out, float* __restrict__ out, unsigned* ws) {
  __shared__ __align__(16) ushort Ah[64][72], Al[64][72];
  __shared__ __align__(16) ushort Bh[128][72], Bl[128][72];
  __shared__ float s_wi[128], s_bi0[128], s_bi1[128];
  unsigned* dslots = ws + 8192;        // 256 slots x 32 stride
  unsigned* dflag = ws + 8192 + 8192;
  const int tid = threadIdx.x;
  const int CG = blockIdx.x & 15, RQ = blockIdx.x >> 4;
  const int row0 = RQ * 64, hcol0 = CG * 32;
  const int lane = tid & 63, wv = tid >> 6;
  const int wm = wv & 3, wn = wv >> 2;
  const int mr = lane & 15, kg = lane >> 4;

  if (tid < 128) {
    const int jsrc = (tid >> 5) * HH + hcol0 + (tid & 31);
    s_wi[tid] = w_ih0[jsrc];
    s_bi0[tid] = b0[jsrc];
    s_bi1[tid] = b1[jsrc];
  }
  const int hl2 = wn * 16 + mr;
  const int hcol = hcol0 + hl2;
  const float wo = w_out[hcol];
  const float bo = b_out[0];
  unsigned p = 0;

  for (int d = 0; d < HOR; ++d) {
    const int cur = d & 1, nxt = cur ^ 1;
    const int ub = d & 1, nb = ub ^ 1;

    // =================== phase L0 ===================
    {
      const ushort* __restrict__ Ahg = &H0h[cur][0][0];
      const ushort* __restrict__ Alg = &H0l[cur][0][0];
      f32x4 acc[4];
#pragma unroll
      for (int g = 0; g < 4; ++g) acc[g] = (f32x4){0.f, 0.f, 0.f, 0.f};

      for (int kt = 0; kt < 8; ++kt) {
        const int k0 = kt * 64;
        __syncthreads();
        {
          const int m = tid >> 3, kk = (tid & 7) * 8;
          *(ushort8*)&Ah[m][kk] = *(const ushort8*)&Ahg[(row0 + m) * HH + k0 + kk];
          *(ushort8*)&Al[m][kk] = *(const ushort8*)&Alg[(row0 + m) * HH + k0 + kk];
        }
#pragma unroll
        for (int i = 0; i < 2; ++i) {
          const int q = i * 512 + tid;
          const int j2 = q >> 3, kk = (q & 7) * 8;
          const int jsrc = (j2 >> 5) * HH + hcol0 + (j2 & 31);
          *(ushort8*)&Bh[j2][kk] = *(const ushort8*)&Whh0h[jsrc][k0 + kk];
          *(ushort8*)&Bl[j2][kk] = *(const ushort8*)&Whh0l[jsrc][k0 + kk];
        }
        __syncthreads();
#pragma unroll
        for (int ks2 = 0; ks2 < 2; ++ks2) {
          const int ko = ks2 * 32 + kg * 8;
          const bf16x8 ah = *(const bf16x8*)&Ah[wm * 16 + mr][ko];
          const bf16x8 al = *(const bf16x8*)&Al[wm * 16 + mr][ko];
#pragma unroll
          for (int g = 0; g < 4; ++g) {
            const bf16x8 bh = *(const bf16x8*)&Bh[g * 32 + wn * 16 + mr][ko];
            const bf16x8 bl = *(const bf16x8*)&Bl[g * 32 + wn * 16 + mr][ko];
            acc[g] = __builtin_amdgcn_mfma_f32_16x16x32_bf16(ah, bh, acc[g], 0, 0, 0);
            acc[g] = __builtin_amdgcn_mfma_f32_16x16x32_bf16(ah, bl, acc[g], 0, 0, 0);
            acc[g] = __builtin_amdgcn_mfma_f32_16x16x32_bf16(al, bh, acc[g], 0, 0, 0);
          }
        }
      }
#pragma unroll
      for (int r = 0; r < 4; ++r) {
        const int row = row0 + wm * 16 + kg * 4 + r;
        const float u = g_u[ub][row];
        const float iv = acc[0][r] + u * s_wi[hl2] + s_bi0[hl2];
        const float fv = acc[1][r] + u * s_wi[32 + hl2] + s_bi0[32 + hl2];
        const float gv = acc[2][r] + u * s_wi[64 + hl2] + s_bi0[64 + hl2];
        const float ov = acc[3][r] + u * s_wi[96 + hl2] + s_bi0[96 + hl2];
        float c = g_C0[row][hcol];
        const float h = cellupd(iv, fv, gv, ov, c);
        g_C0[row][hcol] = c;
        const ushort hh = f2bf(h);
        H0h[nxt][row][hcol] = hh;
        H0l[nxt][row][hcol] = f2bf(h - bf2f(hh));
        if (CG == 0 && wn == 0 && mr == 0) {
          g_u[nb][row] = bo;
          out[row * HOR + d] = bo;
        }
      }
    }
    gbar<DWG>(dslots, dflag, ++p);

    // =================== phase L1 ===================
    {
      f32x4 acc[4];
#pragma unroll
      for (int g = 0; g < 4; ++g) acc[g] = (f32x4){0.f, 0.f, 0.f, 0.f};

#pragma unroll
      for (int src = 0; src < 2; ++src) {
        const ushort* __restrict__ Ahg = src ? &H1h[cur][0][0] : &H0h[nxt][0][0];
        const ushort* __restrict__ Alg = src ? &H1l[cur][0][0] : &H0l[nxt][0][0];
        const ushort* __restrict__ Bhg = src ? &Whh1h[0][0] : &Wih1h[0][0];
        const ushort* __restrict__ Blg = src ? &Whh1l[0][0] : &Wih1l[0][0];
        for (int kt = 0; kt < 8; ++kt) {
          const int k0 = kt * 64;
          __syncthreads();
          {
            const int m = tid >> 3, kk = (tid & 7) * 8;
            *(ushort8*)&Ah[m][kk] = *(const ushort8*)&Ahg[(row0 + m) * HH + k0 + kk];
            *(ushort8*)&Al[m][kk] = *(const ushort8*)&Alg[(row0 + m) * HH + k0 + kk];
          }
#pragma unroll
          for (int i = 0; i < 2; ++i) {
            const int q = i * 512 + tid;
            const int j2 = q >> 3, kk = (q & 7) * 8;
            const int jsrc = (j2 >> 5) * HH + hcol0 + (j2 & 31);
            *(ushort8*)&Bh[j2][kk] = *(const ushort8*)&Bhg[jsrc * HH + k0 + kk];
            *(ushort8*)&Bl[j2][kk] = *(const ushort8*)&Blg[jsrc * HH + k0 + kk];
          }
          __syncthreads();
#pragma unroll
          for (int ks2 = 0; ks2 < 2; ++ks2) {
            const int ko = ks2 * 32 + kg * 8;
            const bf16x8 ah = *(const bf16x8*)&Ah[wm * 16 + mr][ko];
            const bf16x8 al = *(const bf16x8*)&Al[wm * 16 + mr][ko];
#pragma unroll
            for (int g = 0; g < 4; ++g) {
              const bf16x8 bh = *(const bf16x8*)&Bh[g * 32 + wn * 16 + mr][ko];
              const bf16x8 bl = *(const bf16x8*)&Bl[g * 32 + wn * 16 + mr][ko];
              acc[g] = __builtin_amdgcn_mfma_f32_16x16x32_bf16(ah, bh, acc[g], 0, 0, 0);
              acc[g] = __builtin_amdgcn_mfma_f32_16x16x32_bf16(ah, bl, acc[g], 0, 0, 0);
              acc[g] = __builtin_amdgcn_mfma_f32_16x16x32_bf16(al, bh, acc[g], 0, 0, 0);
            }
          }
        }
      }

      float pp[4];
#pragma unroll
      for (int r = 0; r < 4; ++r) {
        const int row = row0 + wm * 16 + kg * 4 + r;
        const float iv = acc[0][r] + s_bi1[hl2];
        const float fv = acc[1][r] + s_bi1[32 + hl2];
        const float gv = acc[2][r] + s_bi1[64 + hl2];
        const float ov = acc[3][r] + s_bi1[96 + hl2];
        float c = g_C1[row][hcol];
        const float h = cellupd(iv, fv, gv, ov, c);
        g_C1[row][hcol] = c;
        const ushort hh = f2bf(h);
        H1h[nxt][row][hcol] = hh;
        H1l[nxt][row][hcol] = f2bf(h - bf2f(hh));
        pp[r] = h * wo;
      }
#pragma unroll
      for (int off = 1; off < 16; off <<= 1) {
#pragma unroll
        for (int r = 0; r < 4; ++r) pp[r] += __shfl_xor(pp[r], off);
      }
      if (mr == 0) {
#pragma unroll
        for (int r = 0; r < 4; ++r) {
          const int row = row0 + wm * 16 + kg * 4 + r;
          atomicAdd(&g_u[nb][row], pp[r]);
          atomicAdd(&out[row * HOR + d], pp[r]);
        }
      }
    }
    gbar<DWG>(dslots, dflag, ++p);
  }
}

extern "C" void kernel_launch(void* const* d_in, const int* in_sizes, int n_in,
                              void* d_out, int out_size, void* d_ws, size_t ws_size,
                              hipStream_t stream) {
  (void)in_sizes; (void)n_in; (void)out_size; (void)ws_size;
  const float* x = (const float*)d_in[0];
  const float* init_input = (const float*)d_in[1];
  const float* w_ih0 = (const float*)d_in[2];
  const float* w_hh0 = (const float*)d_in[3];
  const float* b0 = (const float*)d_in[4];
  const float* w_ih1 = (const float*)d_in[5];
  const float* w_hh1 = (const float*)d_in[6];
  const float* b1 = (const float*)d_in[7];
  const float* w_out = (const float*)d_in[8];
  const float* b_out = (const float*)d_in[9];
  float* out = (float*)d_out;

  // ws layout (unsigned): [0..4095] enc slots, [4096] enc flag,
  // [8192..16383] dec slots, [16384] dec flag.
  hipMemsetAsync(d_ws, 0, 17000 * sizeof(unsigned), stream);
  prep_split<<<2048, 512, 0, stream>>>(w_hh0, w_ih1, w_hh1);
  enc_kernel<<<EWG, ETH, 0, stream>>>(x, init_input, w_ih0, b0, b1,
                                      (unsigned*)d_ws);
  dec_all<<<DWG, 512, 0, stream>>>(w_ih0, b0, b1, w_out, b_out, out,
                                   (unsigned*)d_ws);
}

// Round 19
// 11981.059 us; speedup vs baseline: 1.2056x; 1.2056x over previous
//
#include <hip/hip_runtime.h>
#include <math.h>

// Problem constants (fixed by setup_inputs)
#define BB  64      // batch
#define TT  512     // seq len
#define HH  512     // hidden
#define RR  1024    // decode rows = B*S
#define HOR 64      // horizon

// encoder geometry
#define EWG 128     // encoder WGs (each owns 4 hcols = 16 gate-rows/matrix)
#define ETH 512     // threads (8 waves)

typedef unsigned short ushort;
typedef unsigned long long u64;
typedef __attribute__((ext_vector_type(8))) short bf16x8;     // 8 bf16 (4 VGPRs)
typedef __attribute__((ext_vector_type(8))) unsigned short ushort8;
typedef __attribute__((ext_vector_type(4))) float f32x4;

// Persistent state in device globals (re-initialized every launch)
__device__ float g_c0[BB][HH];
__device__ float g_c1[BB][HH];
__device__ float g_C0[RR][HH];
__device__ float g_C1[RR][HH];
__device__ float g_u[2][RR];       // u double-buffer: g_u[d&1] feeds step d
// encoder h state, split-bf16 (hi + lo residual)
__device__ ushort Eh0h[2][BB][HH], Eh0l[2][BB][HH];
__device__ ushort Eh1h[2][BB][HH], Eh1l[2][BB][HH];
// split-bf16 decoder state (hi + lo residual; GEMM A operands)
__device__ ushort H0h[2][RR][HH], H0l[2][RR][HH];
__device__ ushort H1h[2][RR][HH], H1l[2][RR][HH];
// split-bf16 weights (prep kernel, once per launch)
__device__ ushort Whh0h[4 * HH][HH], Whh0l[4 * HH][HH];
__device__ ushort Wih1h[4 * HH][HH], Wih1l[4 * HH][HH];
__device__ ushort Whh1h[4 * HH][HH], Whh1l[4 * HH][HH];

__device__ __forceinline__ float sigf(float v) { return 1.0f / (1.0f + expf(-v)); }

__device__ __forceinline__ float cellupd(float iv, float fv, float gv, float ov, float& c) {
  c = sigf(fv) * c + sigf(iv) * tanhf(gv);
  return sigf(ov) * tanhf(c);
}

// bf16 RNE helpers
__device__ __forceinline__ ushort f2bf(float x) {
  unsigned u = __float_as_uint(x);
  unsigned r = u + 0x7FFFu + ((u >> 16) & 1u);
  return (ushort)(r >> 16);
}
__device__ __forceinline__ float bf2f(ushort h) {
  return __uint_as_float(((unsigned)h) << 16);
}

// ---- Fence-hoisted barrier, 128 WGs, DIRECT POLL (R17-best; master-flag
// variant regressed in R18). Arrival: ONE wbl2 fence + relaxed slot store.
// Wait: lanes poll all slots in parallel (relaxed agent atomics), then ONE
// inv fence. SAFETY (R2/R4 hangs): ~114KB LDS -> 1 WG/CU; 128 WGs vs 256
// CUs = 2x co-residency slack. Keep it so.
__device__ __forceinline__ void ebar_arrive(unsigned* slots, unsigned p) {
  __syncthreads();
  if (threadIdx.x == 0) {
    __threadfence();  // wbl2: publish this WG's writes
    __hip_atomic_store(slots + blockIdx.x * 32, p, __ATOMIC_RELAXED,
                       __HIP_MEMORY_SCOPE_AGENT);
  }
}
__device__ __forceinline__ void ebar_wait(unsigned* slots, unsigned p) {
  if (threadIdx.x < EWG) {
    while (__hip_atomic_load(slots + threadIdx.x * 32, __ATOMIC_RELAXED,
                             __HIP_MEMORY_SCOPE_AGENT) < p)
      __builtin_amdgcn_s_sleep(1);
  }
  __syncthreads();
  if (threadIdx.x == 0) __threadfence();  // inv: fresh reads of peers' state
  __syncthreads();
}

// ======================= PREP: split weights to bf16 hi/lo =======================
__global__ __launch_bounds__(512) void prep_split(
    const float* __restrict__ whh0, const float* __restrict__ wih1,
    const float* __restrict__ whh1) {
  const int i = blockIdx.x * 512 + threadIdx.x;  // grid 2048 -> 1M elements
  float a = whh0[i];
  ushort h = f2bf(a);
  (&Whh0h[0][0])[i] = h;
  (&Whh0l[0][0])[i] = f2bf(a - bf2f(h));
  a = wih1[i];
  h = f2bf(a);
  (&Wih1h[0][0])[i] = h;
  (&Wih1l[0][0])[i] = f2bf(a - bf2f(h));
  a = whh1[i];
  h = f2bf(a);
  (&Whh1h[0][0])[i] = h;
  (&Whh1l[0][0])[i] = f2bf(a - bf2f(h));
}

// swizzled ushort offset within a 16x512 weight plane for (row jl, chunk ck)
__device__ __forceinline__ int wswz(int jl, int ck) {
  return jl * 512 + (((ck & 56) | ((ck ^ jl) & 7)) << 3);
}

#define GST 20  // gate-exchange row stride (floats); 80B = 16B-aligned

// ======================= ENCODER (persistent, split-bf16 MFMA; R17 body) =======
__global__ __launch_bounds__(ETH, 2) void enc_kernel(
    const float* __restrict__ x, const float* __restrict__ init_input,
    const float* __restrict__ w_ih0, const float* __restrict__ b0,
    const float* __restrict__ b1, unsigned* ws) {
  const int wg = blockIdx.x;
  const int tid = threadIdx.x;
  const int hcol0 = wg * 4;
  unsigned* eslots = ws;               // 128 slots x 32 stride
  unsigned* wsI = ws + 4096;

  __shared__ __align__(16) ushort sW[6][16 * 512];  // [mat*2+half]
  __shared__ float s_gb0[64 * GST];   // [b][hl*4+gate] (stride-padded)
  __shared__ float s_gb1a[64 * GST];
  __shared__ float s_gb1b[64 * GST];
  __shared__ float s_wih0[16], s_b0[16], s_b1[16];

  // ---- load resident weight slices (once): 6 planes x 1024 chunks ----
  for (int i = tid; i < 6 * 1024; i += ETH) {
    const int plane = i >> 10, c = i & 1023;
    const int row = c >> 6, ck = c & 63;
    const int jsrc = (row >> 2) * HH + hcol0 + (row & 3);
    const ushort* src;
    switch (plane) {
      case 0: src = &Whh0h[0][0]; break;
      case 1: src = &Whh0l[0][0]; break;
      case 2: src = &Wih1h[0][0]; break;
      case 3: src = &Wih1l[0][0]; break;
      case 4: src = &Whh1h[0][0]; break;
      default: src = &Whh1l[0][0]; break;
    }
    *(ushort8*)&sW[plane][wswz(row, ck)] =
        *(const ushort8*)&src[jsrc * HH + ck * 8];
  }
  if (tid < 16) {  // jl = gate*4 + hl
    const int jsrc = (tid >> 2) * HH + hcol0 + (tid & 3);
    s_wih0[tid] = w_ih0[jsrc];
    s_b0[tid] = b0[jsrc];
    s_b1[tid] = b1[jsrc];
  }
  {  // zero-init h state (published by barrier's wbl2 fence)
    const int gid = wg * ETH + tid;  // 65536 threads; 8192 ushort8 quads
    if (gid < 8192) {
      const int o = gid * 8;
      *(ushort8*)&(&Eh0h[0][0][0])[o] = (ushort8)(0);
      *(ushort8*)&(&Eh0l[0][0][0])[o] = (ushort8)(0);
      *(ushort8*)&(&Eh1h[0][0][0])[o] = (ushort8)(0);
      *(ushort8*)&(&Eh1l[0][0][0])[o] = (ushort8)(0);
    }
    if (tid < 256) {  // own c slice (4 hcols x 64 b): self-write-self-read
      const int b = tid >> 2, hc = hcol0 + (tid & 3);
      g_c0[b][hc] = 0.f;
      g_c1[b][hc] = 0.f;
    }
  }
  ebar_arrive(wsI, 1);
  ebar_wait(wsI, 1);

  const int lane = tid & 63, wv = tid >> 6;
  const int grp = wv >> 2;      // 0: h0 -> acc0+acc1a; 1: h1 -> acc1b
  const int mh = wv & 3;        // m-tile: batch rows mh*16..+15
  const int mr = lane & 15, kg = lane >> 4;
  const int arow = mh * 16 + mr;
  // cell indices
  const int cb = tid >> 2, chl = tid & 3;
  const int chcol = hcol0 + chl;

  unsigned p = 1;
  for (int tk = 1; tk <= TT + 1; ++tk) {
    const int cur = (tk - 1) & 1, nxt = tk & 1;
    const bool do0 = (tk <= TT), do1 = (tk >= 2);

    f32x4 acc0 = {0.f, 0.f, 0.f, 0.f};
    f32x4 acc1 = {0.f, 0.f, 0.f, 0.f};
    bf16x8 abuf[16];

    if (grp == 0) {
      const ushort* __restrict__ hrow = &Eh0h[cur][arow][0];
      // ---- pass 1: hi fragments, bulk load then MFMA ----
#pragma unroll
      for (int i = 0; i < 16; ++i)
        abuf[i] = *(const bf16x8*)&hrow[(i >> 1) * 64 + (i & 1) * 32 + kg * 8];
#pragma unroll
      for (int i = 0; i < 16; ++i) {
        const int ck = (i >> 1) * 8 + (i & 1) * 4 + kg;
        if (do0) {
          const bf16x8 bh = *(const bf16x8*)&sW[0][wswz(mr, ck)];
          const bf16x8 bl = *(const bf16x8*)&sW[1][wswz(mr, ck)];
          acc0 = __builtin_amdgcn_mfma_f32_16x16x32_bf16(abuf[i], bh, acc0, 0, 0, 0);
          acc0 = __builtin_amdgcn_mfma_f32_16x16x32_bf16(abuf[i], bl, acc0, 0, 0, 0);
        }
        if (do1) {
          const bf16x8 bh = *(const bf16x8*)&sW[2][wswz(mr, ck)];
          const bf16x8 bl = *(const bf16x8*)&sW[3][wswz(mr, ck)];
          acc1 = __builtin_amdgcn_mfma_f32_16x16x32_bf16(abuf[i], bh, acc1, 0, 0, 0);
          acc1 = __builtin_amdgcn_mfma_f32_16x16x32_bf16(abuf[i], bl, acc1, 0, 0, 0);
        }
      }
      // ---- pass 2: lo fragments x hi weights ----
      const ushort* __restrict__ lrow = &Eh0l[cur][arow][0];
#pragma unroll
      for (int i = 0; i < 16; ++i)
        abuf[i] = *(const bf16x8*)&lrow[(i >> 1) * 64 + (i & 1) * 32 + kg * 8];
#pragma unroll
      for (int i = 0; i < 16; ++i) {
        const int ck = (i >> 1) * 8 + (i & 1) * 4 + kg;
        if (do0) {
          const bf16x8 bh = *(const bf16x8*)&sW[0][wswz(mr, ck)];
          acc0 = __builtin_amdgcn_mfma_f32_16x16x32_bf16(abuf[i], bh, acc0, 0, 0, 0);
        }
        if (do1) {
          const bf16x8 bh = *(const bf16x8*)&sW[2][wswz(mr, ck)];
          acc1 = __builtin_amdgcn_mfma_f32_16x16x32_bf16(abuf[i], bh, acc1, 0, 0, 0);
        }
      }
    } else if (do1) {
      const ushort* __restrict__ hrow = &Eh1h[nxt][arow][0];
#pragma unroll
      for (int i = 0; i < 16; ++i)
        abuf[i] = *(const bf16x8*)&hrow[(i >> 1) * 64 + (i & 1) * 32 + kg * 8];
#pragma unroll
      for (int i = 0; i < 16; ++i) {
        const int ck = (i >> 1) * 8 + (i & 1) * 4 + kg;
        const bf16x8 bh = *(const bf16x8*)&sW[4][wswz(mr, ck)];
        const bf16x8 bl = *(const bf16x8*)&sW[5][wswz(mr, ck)];
        acc1 = __builtin_amdgcn_mfma_f32_16x16x32_bf16(abuf[i], bh, acc1, 0, 0, 0);
        acc1 = __builtin_amdgcn_mfma_f32_16x16x32_bf16(abuf[i], bl, acc1, 0, 0, 0);
      }
      const ushort* __restrict__ lrow = &Eh1l[nxt][arow][0];
#pragma unroll
      for (int i = 0; i < 16; ++i)
        abuf[i] = *(const bf16x8*)&lrow[(i >> 1) * 64 + (i & 1) * 32 + kg * 8];
#pragma unroll
      for (int i = 0; i < 16; ++i) {
        const int ck = (i >> 1) * 8 + (i & 1) * 4 + kg;
        const bf16x8 bh = *(const bf16x8*)&sW[4][wswz(mr, ck)];
        acc1 = __builtin_amdgcn_mfma_f32_16x16x32_bf16(abuf[i], bh, acc1, 0, 0, 0);
      }
    }

    // ---- gate exchange: C row (batch) = mh*16 + kg*4 + r, col jl = mr ----
    {
      const int slot = (mr & 3) * 4 + (mr >> 2);  // [hl][gate]
#pragma unroll
      for (int r = 0; r < 4; ++r) {
        const int b = mh * 16 + kg * 4 + r;
        if (grp == 0) {
          if (do0) s_gb0[b * GST + slot] = acc0[r];
          if (do1) s_gb1a[b * GST + slot] = acc1[r];
        } else if (do1) {
          s_gb1b[b * GST + slot] = acc1[r];
        }
      }
    }
    __syncthreads();

    // ---- cell updates: thread -> (b = tid>>2, hl = tid&3), tid < 256 ----
    if (tid < 256) {
      if (do0) {  // cell0 -> h0^{tk}
        const float xv = x[cb * TT + (tk - 1)];
        const float4 gb = *(const float4*)&s_gb0[cb * GST + chl * 4];
        const float iv = gb.x + xv * s_wih0[chl] + s_b0[chl];
        const float fv = gb.y + xv * s_wih0[4 + chl] + s_b0[4 + chl];
        const float gv = gb.z + xv * s_wih0[8 + chl] + s_b0[8 + chl];
        const float ov = gb.w + xv * s_wih0[12 + chl] + s_b0[12 + chl];
        float c = g_c0[cb][chcol];
        const float h = cellupd(iv, fv, gv, ov, c);
        g_c0[cb][chcol] = c;
        const ushort hh = f2bf(h);
        Eh0h[nxt][cb][chcol] = hh;
        Eh0l[nxt][cb][chcol] = f2bf(h - bf2f(hh));
      }
      if (do1) {  // cell1 -> h1^{tk-1}
        const float4 ga = *(const float4*)&s_gb1a[cb * GST + chl * 4];
        const float4 gbb = *(const float4*)&s_gb1b[cb * GST + chl * 4];
        const float iv = ga.x + gbb.x + s_b1[chl];
        const float fv = ga.y + gbb.y + s_b1[4 + chl];
        const float gv = ga.z + gbb.z + s_b1[8 + chl];
        const float ov = ga.w + gbb.w + s_b1[12 + chl];
        float c = g_c1[cb][chcol];
        const float h = cellupd(iv, fv, gv, ov, c);
        g_c1[cb][chcol] = c;
        const ushort hh = f2bf(h);
        Eh1h[cur][cb][chcol] = hh;
        Eh1l[cur][cb][chcol] = f2bf(h - bf2f(hh));
      }
    }
    ebar_arrive(eslots, ++p);
    ebar_wait(eslots, p);
  }

  // ---- expand final states over n_samples: row r = b*16+s ----
  {
    {  // ushort8 slots: RR*HH/8 = 65536 == grid threads
      const int idx = wg * ETH + tid;
      const int r = idx >> 6, k8 = (idx & 63) * 8, b = r >> 4;
      *(ushort8*)&H0h[0][r][k8] = *(const ushort8*)&Eh0h[0][b][k8];
      *(ushort8*)&H0l[0][r][k8] = *(const ushort8*)&Eh0l[0][b][k8];
      *(ushort8*)&H1h[0][r][k8] = *(const ushort8*)&Eh1h[0][b][k8];
      *(ushort8*)&H1l[0][r][k8] = *(const ushort8*)&Eh1l[0][b][k8];
    }
    // C expansion: OWN hcols only (c is local to this WG)
    for (int i = tid; i < RR * 4; i += ETH) {
      const int r = i >> 2, hc = hcol0 + (i & 3), b = r >> 4;
      g_C0[r][hc] = g_c0[b][hc];
      g_C1[r][hc] = g_c1[b][hc];
    }
    const int gid = wg * ETH + tid;
    if (gid < RR) g_u[0][gid] = init_input[gid];
  }
}

// ======================= DECODER (per-step, reg-staged pipelined GEMMs) ========
// R12-verified math; new: tile kt+1 global loads issued into registers BEFORE
// the MFMAs of tile kt (6 x bf16x8 regs), hiding L2/L3 latency under compute.

__global__ __launch_bounds__(512, 4) void dec_l0(
    const float* __restrict__ w_ih0, const float* __restrict__ b0,
    const float* __restrict__ b_out, float* __restrict__ out, int d) {
  __shared__ __align__(16) ushort Ah[64][72], Al[64][72];
  __shared__ __align__(16) ushort Bh[128][72], Bl[128][72];
  __shared__ float s_wi[128], s_bi[128];
  const int tid = threadIdx.x;
  const int CG = blockIdx.x & 15, RQ = blockIdx.x >> 4;
  const int row0 = RQ * 64, hcol0 = CG * 32;
  const int lane = tid & 63, wv = tid >> 6;
  const int wm = wv & 3, wn = wv >> 2;
  const int mr = lane & 15, kg = lane >> 4;

  if (tid < 128) {
    const int jsrc = (tid >> 5) * HH + hcol0 + (tid & 31);
    s_wi[tid] = w_ih0[jsrc];
    s_bi[tid] = b0[jsrc];
  }

  const int cur = d & 1, nxt = cur ^ 1;
  const ushort* __restrict__ Ahg = &H0h[cur][0][0];
  const ushort* __restrict__ Alg = &H0l[cur][0][0];

  // staging indices (fixed per thread)
  const int mA = tid >> 3, kkA = (tid & 7) * 8;
  const int j2a = tid >> 3, j2b = 64 + (tid >> 3);
  const int aoff = (row0 + mA) * HH + kkA;
  const int b0off = ((j2a >> 5) * HH + hcol0 + (j2a & 31)) * HH + kkA;
  const int b1off = ((j2b >> 5) * HH + hcol0 + (j2b & 31)) * HH + kkA;
  const ushort* __restrict__ WBh = &Whh0h[0][0];
  const ushort* __restrict__ WBl = &Whh0l[0][0];

  f32x4 acc[4];
#pragma unroll
  for (int g = 0; g < 4; ++g) acc[g] = (f32x4){0.f, 0.f, 0.f, 0.f};

  // preload tile 0
  bf16x8 rAh = *(const bf16x8*)&Ahg[aoff];
  bf16x8 rAl = *(const bf16x8*)&Alg[aoff];
  bf16x8 rB0h = *(const bf16x8*)&WBh[b0off];
  bf16x8 rB0l = *(const bf16x8*)&WBl[b0off];
  bf16x8 rB1h = *(const bf16x8*)&WBh[b1off];
  bf16x8 rB1l = *(const bf16x8*)&WBl[b1off];

  for (int kt = 0; kt < 8; ++kt) {
    __syncthreads();  // previous MFMAs done reading LDS
    *(bf16x8*)&Ah[mA][kkA] = rAh;
    *(bf16x8*)&Al[mA][kkA] = rAl;
    *(bf16x8*)&Bh[j2a][kkA] = rB0h;
    *(bf16x8*)&Bl[j2a][kkA] = rB0l;
    *(bf16x8*)&Bh[j2b][kkA] = rB1h;
    *(bf16x8*)&Bl[j2b][kkA] = rB1l;
    __syncthreads();
    if (kt < 7) {  // issue next-tile loads; complete under the MFMAs below
      const int k0n = (kt + 1) * 64;
      rAh = *(const bf16x8*)&Ahg[aoff + k0n];
      rAl = *(const bf16x8*)&Alg[aoff + k0n];
      rB0h = *(const bf16x8*)&WBh[b0off + k0n];
      rB0l = *(const bf16x8*)&WBl[b0off + k0n];
      rB1h = *(const bf16x8*)&WBh[b1off + k0n];
      rB1l = *(const bf16x8*)&WBl[b1off + k0n];
    }
#pragma unroll
    for (int ks2 = 0; ks2 < 2; ++ks2) {
      const int ko = ks2 * 32 + kg * 8;
      const bf16x8 ah = *(const bf16x8*)&Ah[wm * 16 + mr][ko];
      const bf16x8 al = *(const bf16x8*)&Al[wm * 16 + mr][ko];
#pragma unroll
      for (int g = 0; g < 4; ++g) {
        const bf16x8 bh = *(const bf16x8*)&Bh[g * 32 + wn * 16 + mr][ko];
        const bf16x8 bl = *(const bf16x8*)&Bl[g * 32 + wn * 16 + mr][ko];
        acc[g] = __builtin_amdgcn_mfma_f32_16x16x32_bf16(ah, bh, acc[g], 0, 0, 0);
        acc[g] = __builtin_amdgcn_mfma_f32_16x16x32_bf16(ah, bl, acc[g], 0, 0, 0);
        acc[g] = __builtin_amdgcn_mfma_f32_16x16x32_bf16(al, bh, acc[g], 0, 0, 0);
      }
    }
  }

  const int hl2 = wn * 16 + mr;
  const int hcol = hcol0 + hl2;
  const int ub = d & 1, nb = ub ^ 1;
  const float bo = b_out[0];
#pragma unroll
  for (int r = 0; r < 4; ++r) {
    const int row = row0 + wm * 16 + kg * 4 + r;
    const float u = g_u[ub][row];
    const float iv = acc[0][r] + u * s_wi[hl2] + s_bi[hl2];
    const float fv = acc[1][r] + u * s_wi[32 + hl2] + s_bi[32 + hl2];
    const float gv = acc[2][r] + u * s_wi[64 + hl2] + s_bi[64 + hl2];
    const float ov = acc[3][r] + u * s_wi[96 + hl2] + s_bi[96 + hl2];
    float c = g_C0[row][hcol];
    const float h = cellupd(iv, fv, gv, ov, c);
    g_C0[row][hcol] = c;
    const ushort hh = f2bf(h);
    H0h[nxt][row][hcol] = hh;
    H0l[nxt][row][hcol] = f2bf(h - bf2f(hh));
    if (CG == 0 && wn == 0 && mr == 0) {
      g_u[nb][row] = bo;
      out[row * HOR + d] = bo;
    }
  }
}

__global__ __launch_bounds__(512, 4) void dec_l1(
    const float* __restrict__ b1, const float* __restrict__ w_out,
    float* __restrict__ out, int d) {
  __shared__ __align__(16) ushort Ah[64][72], Al[64][72];
  __shared__ __align__(16) ushort Bh[128][72], Bl[128][72];
  __shared__ float s_bi[128];
  const int tid = threadIdx.x;
  const int CG = blockIdx.x & 15, RQ = blockIdx.x >> 4;
  const int row0 = RQ * 64, hcol0 = CG * 32;
  const int lane = tid & 63, wv = tid >> 6;
  const int wm = wv & 3, wn = wv >> 2;
  const int mr = lane & 15, kg = lane >> 4;

  if (tid < 128) {
    const int jsrc = (tid >> 5) * HH + hcol0 + (tid & 31);
    s_bi[tid] = b1[jsrc];
  }

  const int cur = d & 1, nxt = cur ^ 1;

  const int mA = tid >> 3, kkA = (tid & 7) * 8;
  const int j2a = tid >> 3, j2b = 64 + (tid >> 3);
  const int aoff = (row0 + mA) * HH + kkA;
  const int b0off = ((j2a >> 5) * HH + hcol0 + (j2a & 31)) * HH + kkA;
  const int b1off = ((j2b >> 5) * HH + hcol0 + (j2b & 31)) * HH + kkA;

  f32x4 acc[4];
#pragma unroll
  for (int g = 0; g < 4; ++g) acc[g] = (f32x4){0.f, 0.f, 0.f, 0.f};

#pragma unroll
  for (int src = 0; src < 2; ++src) {
    const ushort* __restrict__ Ahg = src ? &H1h[cur][0][0] : &H0h[nxt][0][0];
    const ushort* __restrict__ Alg = src ? &H1l[cur][0][0] : &H0l[nxt][0][0];
    const ushort* __restrict__ WBh = src ? &Whh1h[0][0] : &Wih1h[0][0];
    const ushort* __restrict__ WBl = src ? &Whh1l[0][0] : &Wih1l[0][0];

    bf16x8 rAh = *(const bf16x8*)&Ahg[aoff];
    bf16x8 rAl = *(const bf16x8*)&Alg[aoff];
    bf16x8 rB0h = *(const bf16x8*)&WBh[b0off];
    bf16x8 rB0l = *(const bf16x8*)&WBl[b0off];
    bf16x8 rB1h = *(const bf16x8*)&WBh[b1off];
    bf16x8 rB1l = *(const bf16x8*)&WBl[b1off];

    for (int kt = 0; kt < 8; ++kt) {
      __syncthreads();
      *(bf16x8*)&Ah[mA][kkA] = rAh;
      *(bf16x8*)&Al[mA][kkA] = rAl;
      *(bf16x8*)&Bh[j2a][kkA] = rB0h;
      *(bf16x8*)&Bl[j2a][kkA] = rB0l;
      *(bf16x8*)&Bh[j2b][kkA] = rB1h;
      *(bf16x8*)&Bl[j2b][kkA] = rB1l;
      __syncthreads();
      if (kt < 7) {
        const int k0n = (kt + 1) * 64;
        rAh = *(const bf16x8*)&Ahg[aoff + k0n];
        rAl = *(const bf16x8*)&Alg[aoff + k0n];
        rB0h = *(const bf16x8*)&WBh[b0off + k0n];
        rB0l = *(const bf16x8*)&WBl[b0off + k0n];
        rB1h = *(const bf16x8*)&WBh[b1off + k0n];
        rB1l = *(const bf16x8*)&WBl[b1off + k0n];
      }
#pragma unroll
      for (int ks2 = 0; ks2 < 2; ++ks2) {
        const int ko = ks2 * 32 + kg * 8;
        const bf16x8 ah = *(const bf16x8*)&Ah[wm * 16 + mr][ko];
        const bf16x8 al = *(const bf16x8*)&Al[wm * 16 + mr][ko];
#pragma unroll
        for (int g = 0; g < 4; ++g) {
          const bf16x8 bh = *(const bf16x8*)&Bh[g * 32 + wn * 16 + mr][ko];
          const bf16x8 bl = *(const bf16x8*)&Bl[g * 32 + wn * 16 + mr][ko];
          acc[g] = __builtin_amdgcn_mfma_f32_16x16x32_bf16(ah, bh, acc[g], 0, 0, 0);
          acc[g] = __builtin_amdgcn_mfma_f32_16x16x32_bf16(ah, bl, acc[g], 0, 0, 0);
          acc[g] = __builtin_amdgcn_mfma_f32_16x16x32_bf16(al, bh, acc[g], 0, 0, 0);
        }
      }
    }
  }

  const int hl2 = wn * 16 + mr;
  const int hcol = hcol0 + hl2;
  const int nb = (d & 1) ^ 1;
  const float wo = w_out[hcol];
  float pp[4];
#pragma unroll
  for (int r = 0; r < 4; ++r) {
    const int row = row0 + wm * 16 + kg * 4 + r;
    const float iv = acc[0][r] + s_bi[hl2];
    const float fv = acc[1][r] + s_bi[32 + hl2];
    const float gv = acc[2][r] + s_bi[64 + hl2];
    const float ov = acc[3][r] + s_bi[96 + hl2];
    float c = g_C1[row][hcol];
    const float h = cellupd(iv, fv, gv, ov, c);
    g_C1[row][hcol] = c;
    const ushort hh = f2bf(h);
    H1h[nxt][row][hcol] = hh;
    H1l[nxt][row][hcol] = f2bf(h - bf2f(hh));
    pp[r] = h * wo;
  }
#pragma unroll
  for (int off = 1; off < 16; off <<= 1) {
#pragma unroll
    for (int r = 0; r < 4; ++r) pp[r] += __shfl_xor(pp[r], off);
  }
  if (mr == 0) {
#pragma unroll
    for (int r = 0; r < 4; ++r) {
      const int row = row0 + wm * 16 + kg * 4 + r;
      atomicAdd(&g_u[nb][row], pp[r]);
      atomicAdd(&out[row * HOR + d], pp[r]);
    }
  }
}

extern "C" void kernel_launch(void* const* d_in, const int* in_sizes, int n_in,
                              void* d_out, int out_size, void* d_ws, size_t ws_size,
                              hipStream_t stream) {
  (void)in_sizes; (void)n_in; (void)out_size; (void)ws_size;
  const float* x = (const float*)d_in[0];
  const float* init_input = (const float*)d_in[1];
  const float* w_ih0 = (const float*)d_in[2];
  const float* w_hh0 = (const float*)d_in[3];
  const float* b0 = (const float*)d_in[4];
  const float* w_ih1 = (const float*)d_in[5];
  const float* w_hh1 = (const float*)d_in[6];
  const float* b1 = (const float*)d_in[7];
  const float* w_out = (const float*)d_in[8];
  const float* b_out = (const float*)d_in[9];
  float* out = (float*)d_out;

  hipMemsetAsync(d_ws, 0, 8192 * sizeof(unsigned), stream);
  prep_split<<<2048, 512, 0, stream>>>(w_hh0, w_ih1, w_hh1);
  enc_kernel<<<EWG, ETH, 0, stream>>>(x, init_input, w_ih0, b0, b1,
                                      (unsigned*)d_ws);
  for (int d = 0; d < HOR; ++d) {
    dec_l0<<<256, 512, 0, stream>>>(w_ih0, b0, b_out, out, d);
    dec_l1<<<256, 512, 0, stream>>>(b1, w_out, out, d);
  }
}

// Round 20
// 10008.076 us; speedup vs baseline: 1.4433x; 1.1971x over previous
//
#include <hip/hip_runtime.h>
#include <math.h>

// Problem constants (fixed by setup_inputs)
#define BB  64      // batch
#define TT  512     // seq len
#define HH  512     // hidden
#define RR  1024    // decode rows = B*S
#define HOR 64      // horizon

// encoder geometry
#define EWG 128     // encoder WGs (each owns 4 hcols = 16 gate-rows/matrix)
#define ETH 512     // threads (8 waves)

typedef unsigned short ushort;
typedef unsigned long long u64;
typedef __attribute__((ext_vector_type(8))) short bf16x8;     // 8 bf16 (4 VGPRs)
typedef __attribute__((ext_vector_type(8))) unsigned short ushort8;
typedef __attribute__((ext_vector_type(4))) float f32x4;

// Persistent state in device globals (re-initialized every launch)
__device__ float g_c0[BB][HH];
__device__ float g_c1[BB][HH];
__device__ float g_C0[RR][HH];
__device__ float g_C1[RR][HH];
__device__ float g_u[2][RR];       // u double-buffer: g_u[d&1] feeds step d
// encoder h state, split-bf16 (hi + lo residual). WRITTEN via relaxed
// agent-scope atomic stores (write-through to L3); READ via normal bulk
// vector loads after the wait-side inv fence.
__device__ ushort Eh0h[2][BB][HH], Eh0l[2][BB][HH];
__device__ ushort Eh1h[2][BB][HH], Eh1l[2][BB][HH];
// split-bf16 decoder state (hi + lo residual; GEMM A operands)
__device__ ushort H0h[2][RR][HH], H0l[2][RR][HH];
__device__ ushort H1h[2][RR][HH], H1l[2][RR][HH];
// split-bf16 weights (prep kernel, once per launch)
__device__ ushort Whh0h[4 * HH][HH], Whh0l[4 * HH][HH];
__device__ ushort Wih1h[4 * HH][HH], Wih1l[4 * HH][HH];
__device__ ushort Whh1h[4 * HH][HH], Whh1l[4 * HH][HH];

__device__ __forceinline__ float sigf(float v) { return 1.0f / (1.0f + expf(-v)); }

__device__ __forceinline__ float cellupd(float iv, float fv, float gv, float ov, float& c) {
  c = sigf(fv) * c + sigf(iv) * tanhf(gv);
  return sigf(ov) * tanhf(c);
}

// bf16 RNE helpers
__device__ __forceinline__ ushort f2bf(float x) {
  unsigned u = __float_as_uint(x);
  unsigned r = u + 0x7FFFu + ((u >> 16) & 1u);
  return (ushort)(r >> 16);
}
__device__ __forceinline__ float bf2f(ushort h) {
  return __uint_as_float(((unsigned)h) << 16);
}

// L3-coherent store helpers (relaxed agent atomics; HW-proven R16)
__device__ __forceinline__ void st2a(ushort* p, ushort v) {
  __hip_atomic_store(p, v, __ATOMIC_RELAXED, __HIP_MEMORY_SCOPE_AGENT);
}
__device__ __forceinline__ void st8a(ushort* p, u64 v) {
  __hip_atomic_store((u64*)p, v, __ATOMIC_RELAXED, __HIP_MEMORY_SCOPE_AGENT);
}

// ---- Hybrid-coherence barrier, 128 WGs, direct poll ----
// h is published by ATOMIC stores (write-through), so arrival needs NO
// wbl2 fence: __syncthreads drains vmcnt (atomic stores land in L3), then
// one relaxed slot store. Wait: lanes poll all slots in parallel, then ONE
// __threadfence (the inv half makes peers' L3 h visible to our normal
// bulk loads). SAFETY (R2/R4 hangs): ~114KB LDS -> 1 WG/CU; 128 WGs vs
// 256 CUs = 2x co-residency slack. Keep it so.
__device__ __forceinline__ void ebar_arrive(unsigned* slots, unsigned p) {
  __syncthreads();  // vmcnt drained: all atomic h stores visible in L3
  if (threadIdx.x == 0)
    __hip_atomic_store(slots + blockIdx.x * 32, p, __ATOMIC_RELAXED,
                       __HIP_MEMORY_SCOPE_AGENT);
}
__device__ __forceinline__ void ebar_wait(unsigned* slots, unsigned p) {
  if (threadIdx.x < EWG) {
    while (__hip_atomic_load(slots + threadIdx.x * 32, __ATOMIC_RELAXED,
                             __HIP_MEMORY_SCOPE_AGENT) < p)
      __builtin_amdgcn_s_sleep(1);
  }
  __syncthreads();
  if (threadIdx.x == 0) __threadfence();  // inv: drop stale L2 h lines
  __syncthreads();
}

// ======================= PREP: split weights to bf16 hi/lo =======================
__global__ __launch_bounds__(512) void prep_split(
    const float* __restrict__ whh0, const float* __restrict__ wih1,
    const float* __restrict__ whh1) {
  const int i = blockIdx.x * 512 + threadIdx.x;  // grid 2048 -> 1M elements
  float a = whh0[i];
  ushort h = f2bf(a);
  (&Whh0h[0][0])[i] = h;
  (&Whh0l[0][0])[i] = f2bf(a - bf2f(h));
  a = wih1[i];
  h = f2bf(a);
  (&Wih1h[0][0])[i] = h;
  (&Wih1l[0][0])[i] = f2bf(a - bf2f(h));
  a = whh1[i];
  h = f2bf(a);
  (&Whh1h[0][0])[i] = h;
  (&Whh1l[0][0])[i] = f2bf(a - bf2f(h));
}

// swizzled ushort offset within a 16x512 weight plane for (row jl, chunk ck)
__device__ __forceinline__ int wswz(int jl, int ck) {
  return jl * 512 + (((ck & 56) | ((ck ^ jl) & 7)) << 3);
}

#define GST 20  // gate-exchange row stride (floats); 80B = 16B-aligned

// ======================= ENCODER (persistent, split-bf16 MFMA; R17 body) =======
__global__ __launch_bounds__(ETH, 2) void enc_kernel(
    const float* __restrict__ x, const float* __restrict__ init_input,
    const float* __restrict__ w_ih0, const float* __restrict__ b0,
    const float* __restrict__ b1, unsigned* ws) {
  const int wg = blockIdx.x;
  const int tid = threadIdx.x;
  const int hcol0 = wg * 4;
  unsigned* eslots = ws;               // 128 slots x 32 stride
  unsigned* wsI = ws + 4096;

  __shared__ __align__(16) ushort sW[6][16 * 512];  // [mat*2+half]
  __shared__ float s_gb0[64 * GST];   // [b][hl*4+gate] (stride-padded)
  __shared__ float s_gb1a[64 * GST];
  __shared__ float s_gb1b[64 * GST];
  __shared__ float s_wih0[16], s_b0[16], s_b1[16];

  // ---- load resident weight slices (once): 6 planes x 1024 chunks ----
  for (int i = tid; i < 6 * 1024; i += ETH) {
    const int plane = i >> 10, c = i & 1023;
    const int row = c >> 6, ck = c & 63;
    const int jsrc = (row >> 2) * HH + hcol0 + (row & 3);
    const ushort* src;
    switch (plane) {
      case 0: src = &Whh0h[0][0]; break;
      case 1: src = &Whh0l[0][0]; break;
      case 2: src = &Wih1h[0][0]; break;
      case 3: src = &Wih1l[0][0]; break;
      case 4: src = &Whh1h[0][0]; break;
      default: src = &Whh1l[0][0]; break;
    }
    *(ushort8*)&sW[plane][wswz(row, ck)] =
        *(const ushort8*)&src[jsrc * HH + ck * 8];
  }
  if (tid < 16) {  // jl = gate*4 + hl
    const int jsrc = (tid >> 2) * HH + hcol0 + (tid & 3);
    s_wih0[tid] = w_ih0[jsrc];
    s_b0[tid] = b0[jsrc];
    s_b1[tid] = b1[jsrc];
  }
  {  // zero-init h state via ATOMIC stores (write-through; no fence needed)
    const int gid = wg * ETH + tid;  // 65536 threads; 16384 u64 quads/array
    if (gid < 16384) {
      st8a(&(&Eh0h[0][0][0])[gid * 4], 0ull);
      st8a(&(&Eh0l[0][0][0])[gid * 4], 0ull);
      st8a(&(&Eh1h[0][0][0])[gid * 4], 0ull);
      st8a(&(&Eh1l[0][0][0])[gid * 4], 0ull);
    }
    if (tid < 256) {  // own c slice (4 hcols x 64 b): self-write-self-read
      const int b = tid >> 2, hc = hcol0 + (tid & 3);
      g_c0[b][hc] = 0.f;
      g_c1[b][hc] = 0.f;
    }
  }
  ebar_arrive(wsI, 1);
  ebar_wait(wsI, 1);

  const int lane = tid & 63, wv = tid >> 6;
  const int grp = wv >> 2;      // 0: h0 -> acc0+acc1a; 1: h1 -> acc1b
  const int mh = wv & 3;        // m-tile: batch rows mh*16..+15
  const int mr = lane & 15, kg = lane >> 4;
  const int arow = mh * 16 + mr;
  // cell indices
  const int cb = tid >> 2, chl = tid & 3;
  const int chcol = hcol0 + chl;

  unsigned p = 1;
  for (int tk = 1; tk <= TT + 1; ++tk) {
    const int cur = (tk - 1) & 1, nxt = tk & 1;
    const bool do0 = (tk <= TT), do1 = (tk >= 2);

    f32x4 acc0 = {0.f, 0.f, 0.f, 0.f};
    f32x4 acc1 = {0.f, 0.f, 0.f, 0.f};
    bf16x8 abuf[16];

    if (grp == 0) {
      const ushort* __restrict__ hrow = &Eh0h[cur][arow][0];
      // ---- pass 1: hi fragments, bulk load then MFMA ----
#pragma unroll
      for (int i = 0; i < 16; ++i)
        abuf[i] = *(const bf16x8*)&hrow[(i >> 1) * 64 + (i & 1) * 32 + kg * 8];
#pragma unroll
      for (int i = 0; i < 16; ++i) {
        const int ck = (i >> 1) * 8 + (i & 1) * 4 + kg;
        if (do0) {
          const bf16x8 bh = *(const bf16x8*)&sW[0][wswz(mr, ck)];
          const bf16x8 bl = *(const bf16x8*)&sW[1][wswz(mr, ck)];
          acc0 = __builtin_amdgcn_mfma_f32_16x16x32_bf16(abuf[i], bh, acc0, 0, 0, 0);
          acc0 = __builtin_amdgcn_mfma_f32_16x16x32_bf16(abuf[i], bl, acc0, 0, 0, 0);
        }
        if (do1) {
          const bf16x8 bh = *(const bf16x8*)&sW[2][wswz(mr, ck)];
          const bf16x8 bl = *(const bf16x8*)&sW[3][wswz(mr, ck)];
          acc1 = __builtin_amdgcn_mfma_f32_16x16x32_bf16(abuf[i], bh, acc1, 0, 0, 0);
          acc1 = __builtin_amdgcn_mfma_f32_16x16x32_bf16(abuf[i], bl, acc1, 0, 0, 0);
        }
      }
      // ---- pass 2: lo fragments x hi weights ----
      const ushort* __restrict__ lrow = &Eh0l[cur][arow][0];
#pragma unroll
      for (int i = 0; i < 16; ++i)
        abuf[i] = *(const bf16x8*)&lrow[(i >> 1) * 64 + (i & 1) * 32 + kg * 8];
#pragma unroll
      for (int i = 0; i < 16; ++i) {
        const int ck = (i >> 1) * 8 + (i & 1) * 4 + kg;
        if (do0) {
          const bf16x8 bh = *(const bf16x8*)&sW[0][wswz(mr, ck)];
          acc0 = __builtin_amdgcn_mfma_f32_16x16x32_bf16(abuf[i], bh, acc0, 0, 0, 0);
        }
        if (do1) {
          const bf16x8 bh = *(const bf16x8*)&sW[2][wswz(mr, ck)];
          acc1 = __builtin_amdgcn_mfma_f32_16x16x32_bf16(abuf[i], bh, acc1, 0, 0, 0);
        }
      }
    } else if (do1) {
      const ushort* __restrict__ hrow = &Eh1h[nxt][arow][0];
#pragma unroll
      for (int i = 0; i < 16; ++i)
        abuf[i] = *(const bf16x8*)&hrow[(i >> 1) * 64 + (i & 1) * 32 + kg * 8];
#pragma unroll
      for (int i = 0; i < 16; ++i) {
        const int ck = (i >> 1) * 8 + (i & 1) * 4 + kg;
        const bf16x8 bh = *(const bf16x8*)&sW[4][wswz(mr, ck)];
        const bf16x8 bl = *(const bf16x8*)&sW[5][wswz(mr, ck)];
        acc1 = __builtin_amdgcn_mfma_f32_16x16x32_bf16(abuf[i], bh, acc1, 0, 0, 0);
        acc1 = __builtin_amdgcn_mfma_f32_16x16x32_bf16(abuf[i], bl, acc1, 0, 0, 0);
      }
      const ushort* __restrict__ lrow = &Eh1l[nxt][arow][0];
#pragma unroll
      for (int i = 0; i < 16; ++i)
        abuf[i] = *(const bf16x8*)&lrow[(i >> 1) * 64 + (i & 1) * 32 + kg * 8];
#pragma unroll
      for (int i = 0; i < 16; ++i) {
        const int ck = (i >> 1) * 8 + (i & 1) * 4 + kg;
        const bf16x8 bh = *(const bf16x8*)&sW[4][wswz(mr, ck)];
        acc1 = __builtin_amdgcn_mfma_f32_16x16x32_bf16(abuf[i], bh, acc1, 0, 0, 0);
      }
    }

    // ---- gate exchange: C row (batch) = mh*16 + kg*4 + r, col jl = mr ----
    {
      const int slot = (mr & 3) * 4 + (mr >> 2);  // [hl][gate]
#pragma unroll
      for (int r = 0; r < 4; ++r) {
        const int b = mh * 16 + kg * 4 + r;
        if (grp == 0) {
          if (do0) s_gb0[b * GST + slot] = acc0[r];
          if (do1) s_gb1a[b * GST + slot] = acc1[r];
        } else if (do1) {
          s_gb1b[b * GST + slot] = acc1[r];
        }
      }
    }
    __syncthreads();

    // ---- cell updates: thread -> (b = tid>>2, hl = tid&3), tid < 256 ----
    // h written with ATOMIC stores (write-through L3; published by arrive's
    // vmcnt drain, no wbl2 needed).
    if (tid < 256) {
      if (do0) {  // cell0 -> h0^{tk}
        const float xv = x[cb * TT + (tk - 1)];
        const float4 gb = *(const float4*)&s_gb0[cb * GST + chl * 4];
        const float iv = gb.x + xv * s_wih0[chl] + s_b0[chl];
        const float fv = gb.y + xv * s_wih0[4 + chl] + s_b0[4 + chl];
        const float gv = gb.z + xv * s_wih0[8 + chl] + s_b0[8 + chl];
        const float ov = gb.w + xv * s_wih0[12 + chl] + s_b0[12 + chl];
        float c = g_c0[cb][chcol];
        const float h = cellupd(iv, fv, gv, ov, c);
        g_c0[cb][chcol] = c;
        const ushort hh = f2bf(h);
        st2a(&Eh0h[nxt][cb][chcol], hh);
        st2a(&Eh0l[nxt][cb][chcol], f2bf(h - bf2f(hh)));
      }
      if (do1) {  // cell1 -> h1^{tk-1}
        const float4 ga = *(const float4*)&s_gb1a[cb * GST + chl * 4];
        const float4 gbb = *(const float4*)&s_gb1b[cb * GST + chl * 4];
        const float iv = ga.x + gbb.x + s_b1[chl];
        const float fv = ga.y + gbb.y + s_b1[4 + chl];
        const float gv = ga.z + gbb.z + s_b1[8 + chl];
        const float ov = ga.w + gbb.w + s_b1[12 + chl];
        float c = g_c1[cb][chcol];
        const float h = cellupd(iv, fv, gv, ov, c);
        g_c1[cb][chcol] = c;
        const ushort hh = f2bf(h);
        st2a(&Eh1h[cur][cb][chcol], hh);
        st2a(&Eh1l[cur][cb][chcol], f2bf(h - bf2f(hh)));
      }
    }
    ebar_arrive(eslots, ++p);
    ebar_wait(eslots, p);
  }

  // ---- expand final states over n_samples: row r = b*16+s ----
  // (last ebar_wait's inv makes peers' final h visible to normal loads)
  {
    {  // ushort8 slots: RR*HH/8 = 65536 == grid threads
      const int idx = wg * ETH + tid;
      const int r = idx >> 6, k8 = (idx & 63) * 8, b = r >> 4;
      *(ushort8*)&H0h[0][r][k8] = *(const ushort8*)&Eh0h[0][b][k8];
      *(ushort8*)&H0l[0][r][k8] = *(const ushort8*)&Eh0l[0][b][k8];
      *(ushort8*)&H1h[0][r][k8] = *(const ushort8*)&Eh1h[0][b][k8];
      *(ushort8*)&H1l[0][r][k8] = *(const ushort8*)&Eh1l[0][b][k8];
    }
    // C expansion: OWN hcols only (c is local to this WG)
    for (int i = tid; i < RR * 4; i += ETH) {
      const int r = i >> 2, hc = hcol0 + (i & 3), b = r >> 4;
      g_C0[r][hc] = g_c0[b][hc];
      g_C1[r][hc] = g_c1[b][hc];
    }
    const int gid = wg * ETH + tid;
    if (gid < RR) g_u[0][gid] = init_input[gid];
  }
}

// ======================= DECODER (per-step, reg-staged pipelined; R19) =========
__global__ __launch_bounds__(512, 4) void dec_l0(
    const float* __restrict__ w_ih0, const float* __restrict__ b0,
    const float* __restrict__ b_out, float* __restrict__ out, int d) {
  __shared__ __align__(16) ushort Ah[64][72], Al[64][72];
  __shared__ __align__(16) ushort Bh[128][72], Bl[128][72];
  __shared__ float s_wi[128], s_bi[128];
  const int tid = threadIdx.x;
  const int CG = blockIdx.x & 15, RQ = blockIdx.x >> 4;
  const int row0 = RQ * 64, hcol0 = CG * 32;
  const int lane = tid & 63, wv = tid >> 6;
  const int wm = wv & 3, wn = wv >> 2;
  const int mr = lane & 15, kg = lane >> 4;

  if (tid < 128) {
    const int jsrc = (tid >> 5) * HH + hcol0 + (tid & 31);
    s_wi[tid] = w_ih0[jsrc];
    s_bi[tid] = b0[jsrc];
  }

  const int cur = d & 1, nxt = cur ^ 1;
  const ushort* __restrict__ Ahg = &H0h[cur][0][0];
  const ushort* __restrict__ Alg = &H0l[cur][0][0];

  const int mA = tid >> 3, kkA = (tid & 7) * 8;
  const int j2a = tid >> 3, j2b = 64 + (tid >> 3);
  const int aoff = (row0 + mA) * HH + kkA;
  const int b0off = ((j2a >> 5) * HH + hcol0 + (j2a & 31)) * HH + kkA;
  const int b1off = ((j2b >> 5) * HH + hcol0 + (j2b & 31)) * HH + kkA;
  const ushort* __restrict__ WBh = &Whh0h[0][0];
  const ushort* __restrict__ WBl = &Whh0l[0][0];

  f32x4 acc[4];
#pragma unroll
  for (int g = 0; g < 4; ++g) acc[g] = (f32x4){0.f, 0.f, 0.f, 0.f};

  bf16x8 rAh = *(const bf16x8*)&Ahg[aoff];
  bf16x8 rAl = *(const bf16x8*)&Alg[aoff];
  bf16x8 rB0h = *(const bf16x8*)&WBh[b0off];
  bf16x8 rB0l = *(const bf16x8*)&WBl[b0off];
  bf16x8 rB1h = *(const bf16x8*)&WBh[b1off];
  bf16x8 rB1l = *(const bf16x8*)&WBl[b1off];

  for (int kt = 0; kt < 8; ++kt) {
    __syncthreads();
    *(bf16x8*)&Ah[mA][kkA] = rAh;
    *(bf16x8*)&Al[mA][kkA] = rAl;
    *(bf16x8*)&Bh[j2a][kkA] = rB0h;
    *(bf16x8*)&Bl[j2a][kkA] = rB0l;
    *(bf16x8*)&Bh[j2b][kkA] = rB1h;
    *(bf16x8*)&Bl[j2b][kkA] = rB1l;
    __syncthreads();
    if (kt < 7) {
      const int k0n = (kt + 1) * 64;
      rAh = *(const bf16x8*)&Ahg[aoff + k0n];
      rAl = *(const bf16x8*)&Alg[aoff + k0n];
      rB0h = *(const bf16x8*)&WBh[b0off + k0n];
      rB0l = *(const bf16x8*)&WBl[b0off + k0n];
      rB1h = *(const bf16x8*)&WBh[b1off + k0n];
      rB1l = *(const bf16x8*)&WBl[b1off + k0n];
    }
#pragma unroll
    for (int ks2 = 0; ks2 < 2; ++ks2) {
      const int ko = ks2 * 32 + kg * 8;
      const bf16x8 ah = *(const bf16x8*)&Ah[wm * 16 + mr][ko];
      const bf16x8 al = *(const bf16x8*)&Al[wm * 16 + mr][ko];
#pragma unroll
      for (int g = 0; g < 4; ++g) {
        const bf16x8 bh = *(const bf16x8*)&Bh[g * 32 + wn * 16 + mr][ko];
        const bf16x8 bl = *(const bf16x8*)&Bl[g * 32 + wn * 16 + mr][ko];
        acc[g] = __builtin_amdgcn_mfma_f32_16x16x32_bf16(ah, bh, acc[g], 0, 0, 0);
        acc[g] = __builtin_amdgcn_mfma_f32_16x16x32_bf16(ah, bl, acc[g], 0, 0, 0);
        acc[g] = __builtin_amdgcn_mfma_f32_16x16x32_bf16(al, bh, acc[g], 0, 0, 0);
      }
    }
  }

  const int hl2 = wn * 16 + mr;
  const int hcol = hcol0 + hl2;
  const int ub = d & 1, nb = ub ^ 1;
  const float bo = b_out[0];
#pragma unroll
  for (int r = 0; r < 4; ++r) {
    const int row = row0 + wm * 16 + kg * 4 + r;
    const float u = g_u[ub][row];
    const float iv = acc[0][r] + u * s_wi[hl2] + s_bi[hl2];
    const float fv = acc[1][r] + u * s_wi[32 + hl2] + s_bi[32 + hl2];
    const float gv = acc[2][r] + u * s_wi[64 + hl2] + s_bi[64 + hl2];
    const float ov = acc[3][r] + u * s_wi[96 + hl2] + s_bi[96 + hl2];
    float c = g_C0[row][hcol];
    const float h = cellupd(iv, fv, gv, ov, c);
    g_C0[row][hcol] = c;
    const ushort hh = f2bf(h);
    H0h[nxt][row][hcol] = hh;
    H0l[nxt][row][hcol] = f2bf(h - bf2f(hh));
    if (CG == 0 && wn == 0 && mr == 0) {
      g_u[nb][row] = bo;
      out[row * HOR + d] = bo;
    }
  }
}

__global__ __launch_bounds__(512, 4) void dec_l1(
    const float* __restrict__ b1, const float* __restrict__ w_out,
    float* __restrict__ out, int d) {
  __shared__ __align__(16) ushort Ah[64][72], Al[64][72];
  __shared__ __align__(16) ushort Bh[128][72], Bl[128][72];
  __shared__ float s_bi[128];
  const int tid = threadIdx.x;
  const int CG = blockIdx.x & 15, RQ = blockIdx.x >> 4;
  const int row0 = RQ * 64, hcol0 = CG * 32;
  const int lane = tid & 63, wv = tid >> 6;
  const int wm = wv & 3, wn = wv >> 2;
  const int mr = lane & 15, kg = lane >> 4;

  if (tid < 128) {
    const int jsrc = (tid >> 5) * HH + hcol0 + (tid & 31);
    s_bi[tid] = b1[jsrc];
  }

  const int cur = d & 1, nxt = cur ^ 1;

  const int mA = tid >> 3, kkA = (tid & 7) * 8;
  const int j2a = tid >> 3, j2b = 64 + (tid >> 3);
  const int aoff = (row0 + mA) * HH + kkA;
  const int b0off = ((j2a >> 5) * HH + hcol0 + (j2a & 31)) * HH + kkA;
  const int b1off = ((j2b >> 5) * HH + hcol0 + (j2b & 31)) * HH + kkA;

  f32x4 acc[4];
#pragma unroll
  for (int g = 0; g < 4; ++g) acc[g] = (f32x4){0.f, 0.f, 0.f, 0.f};

#pragma unroll
  for (int src = 0; src < 2; ++src) {
    const ushort* __restrict__ Ahg = src ? &H1h[cur][0][0] : &H0h[nxt][0][0];
    const ushort* __restrict__ Alg = src ? &H1l[cur][0][0] : &H0l[nxt][0][0];
    const ushort* __restrict__ WBh = src ? &Whh1h[0][0] : &Wih1h[0][0];
    const ushort* __restrict__ WBl = src ? &Whh1l[0][0] : &Wih1l[0][0];

    bf16x8 rAh = *(const bf16x8*)&Ahg[aoff];
    bf16x8 rAl = *(const bf16x8*)&Alg[aoff];
    bf16x8 rB0h = *(const bf16x8*)&WBh[b0off];
    bf16x8 rB0l = *(const bf16x8*)&WBl[b0off];
    bf16x8 rB1h = *(const bf16x8*)&WBh[b1off];
    bf16x8 rB1l = *(const bf16x8*)&WBl[b1off];

    for (int kt = 0; kt < 8; ++kt) {
      __syncthreads();
      *(bf16x8*)&Ah[mA][kkA] = rAh;
      *(bf16x8*)&Al[mA][kkA] = rAl;
      *(bf16x8*)&Bh[j2a][kkA] = rB0h;
      *(bf16x8*)&Bl[j2a][kkA] = rB0l;
      *(bf16x8*)&Bh[j2b][kkA] = rB1h;
      *(bf16x8*)&Bl[j2b][kkA] = rB1l;
      __syncthreads();
      if (kt < 7) {
        const int k0n = (kt + 1) * 64;
        rAh = *(const bf16x8*)&Ahg[aoff + k0n];
        rAl = *(const bf16x8*)&Alg[aoff + k0n];
        rB0h = *(const bf16x8*)&WBh[b0off + k0n];
        rB0l = *(const bf16x8*)&WBl[b0off + k0n];
        rB1h = *(const bf16x8*)&WBh[b1off + k0n];
        rB1l = *(const bf16x8*)&WBl[b1off + k0n];
      }
#pragma unroll
      for (int ks2 = 0; ks2 < 2; ++ks2) {
        const int ko = ks2 * 32 + kg * 8;
        const bf16x8 ah = *(const bf16x8*)&Ah[wm * 16 + mr][ko];
        const bf16x8 al = *(const bf16x8*)&Al[wm * 16 + mr][ko];
#pragma unroll
        for (int g = 0; g < 4; ++g) {
          const bf16x8 bh = *(const bf16x8*)&Bh[g * 32 + wn * 16 + mr][ko];
          const bf16x8 bl = *(const bf16x8*)&Bl[g * 32 + wn * 16 + mr][ko];
          acc[g] = __builtin_amdgcn_mfma_f32_16x16x32_bf16(ah, bh, acc[g], 0, 0, 0);
          acc[g] = __builtin_amdgcn_mfma_f32_16x16x32_bf16(ah, bl, acc[g], 0, 0, 0);
          acc[g] = __builtin_amdgcn_mfma_f32_16x16x32_bf16(al, bh, acc[g], 0, 0, 0);
        }
      }
    }
  }

  const int hl2 = wn * 16 + mr;
  const int hcol = hcol0 + hl2;
  const int nb = (d & 1) ^ 1;
  const float wo = w_out[hcol];
  float pp[4];
#pragma unroll
  for (int r = 0; r < 4; ++r) {
    const int row = row0 + wm * 16 + kg * 4 + r;
    const float iv = acc[0][r] + s_bi[hl2];
    const float fv = acc[1][r] + s_bi[32 + hl2];
    const float gv = acc[2][r] + s_bi[64 + hl2];
    const float ov = acc[3][r] + s_bi[96 + hl2];
    float c = g_C1[row][hcol];
    const float h = cellupd(iv, fv, gv, ov, c);
    g_C1[row][hcol] = c;
    const ushort hh = f2bf(h);
    H1h[nxt][row][hcol] = hh;
    H1l[nxt][row][hcol] = f2bf(h - bf2f(hh));
    pp[r] = h * wo;
  }
#pragma unroll
  for (int off = 1; off < 16; off <<= 1) {
#pragma unroll
    for (int r = 0; r < 4; ++r) pp[r] += __shfl_xor(pp[r], off);
  }
  if (mr == 0) {
#pragma unroll
    for (int r = 0; r < 4; ++r) {
      const int row = row0 + wm * 16 + kg * 4 + r;
      atomicAdd(&g_u[nb][row], pp[r]);
      atomicAdd(&out[row * HOR + d], pp[r]);
    }
  }
}

extern "C" void kernel_launch(void* const* d_in, const int* in_sizes, int n_in,
                              void* d_out, int out_size, void* d_ws, size_t ws_size,
                              hipStream_t stream) {
  (void)in_sizes; (void)n_in; (void)out_size; (void)ws_size;
  const float* x = (const float*)d_in[0];
  const float* init_input = (const float*)d_in[1];
  const float* w_ih0 = (const float*)d_in[2];
  const float* w_hh0 = (const float*)d_in[3];
  const float* b0 = (const float*)d_in[4];
  const float* w_ih1 = (const float*)d_in[5];
  const float* w_hh1 = (const float*)d_in[6];
  const float* b1 = (const float*)d_in[7];
  const float* w_out = (const float*)d_in[8];
  const float* b_out = (const float*)d_in[9];
  float* out = (float*)d_out;

  hipMemsetAsync(d_ws, 0, 8192 * sizeof(unsigned), stream);
  prep_split<<<2048, 512, 0, stream>>>(w_hh0, w_ih1, w_hh1);
  enc_kernel<<<EWG, ETH, 0, stream>>>(x, init_input, w_ih0, b0, b1,
                                      (unsigned*)d_ws);
  for (int d = 0; d < HOR; ++d) {
    dec_l0<<<256, 512, 0, stream>>>(w_ih0, b0, b_out, out, d);
    dec_l1<<<256, 512, 0, stream>>>(b1, w_out, out, d);
  }
}

// Round 21
// 9222.759 us; speedup vs baseline: 1.5662x; 1.0851x over previous
//
#include <hip/hip_runtime.h>
#include <math.h>

// Problem constants (fixed by setup_inputs)
#define BB  64      // batch
#define TT  512     // seq len
#define HH  512     // hidden
#define RR  1024    // decode rows = B*S
#define HOR 64      // horizon

// encoder geometry
#define EWG 128     // encoder WGs (each owns 4 hcols = 16 gate-rows/matrix)
#define ETH 512     // threads (8 waves)

typedef unsigned short ushort;
typedef unsigned long long u64;
typedef __attribute__((ext_vector_type(8))) short bf16x8;     // 8 bf16 (4 VGPRs)
typedef __attribute__((ext_vector_type(8))) unsigned short ushort8;
typedef __attribute__((ext_vector_type(4))) float f32x4;

// Persistent state in device globals (re-initialized every launch)
__device__ float g_c0[BB][HH];
__device__ float g_c1[BB][HH];
__device__ float g_C0[RR][HH];
__device__ float g_C1[RR][HH];
__device__ float g_u[2][RR];       // u double-buffer: g_u[d&1] feeds step d
// encoder h state, split-bf16 (hi + lo residual). WRITTEN via relaxed
// agent-scope atomic stores (write-through to L3); READ via normal bulk
// vector loads after the wait-side invalidate.
__device__ ushort Eh0h[2][BB][HH], Eh0l[2][BB][HH];
__device__ ushort Eh1h[2][BB][HH], Eh1l[2][BB][HH];
// split-bf16 decoder state (hi + lo residual; GEMM A operands)
__device__ ushort H0h[2][RR][HH], H0l[2][RR][HH];
__device__ ushort H1h[2][RR][HH], H1l[2][RR][HH];
// split-bf16 weights (prep kernel, once per launch)
__device__ ushort Whh0h[4 * HH][HH], Whh0l[4 * HH][HH];
__device__ ushort Wih1h[4 * HH][HH], Wih1l[4 * HH][HH];
__device__ ushort Whh1h[4 * HH][HH], Whh1l[4 * HH][HH];

__device__ __forceinline__ float sigf(float v) { return 1.0f / (1.0f + expf(-v)); }

__device__ __forceinline__ float cellupd(float iv, float fv, float gv, float ov, float& c) {
  c = sigf(fv) * c + sigf(iv) * tanhf(gv);
  return sigf(ov) * tanhf(c);
}

// bf16 RNE helpers
__device__ __forceinline__ ushort f2bf(float x) {
  unsigned u = __float_as_uint(x);
  unsigned r = u + 0x7FFFu + ((u >> 16) & 1u);
  return (ushort)(r >> 16);
}
__device__ __forceinline__ float bf2f(ushort h) {
  return __uint_as_float(((unsigned)h) << 16);
}

// L3-coherent store helpers (relaxed agent atomics; HW-proven R16/R20)
__device__ __forceinline__ void st2a(ushort* p, ushort v) {
  __hip_atomic_store(p, v, __ATOMIC_RELAXED, __HIP_MEMORY_SCOPE_AGENT);
}
__device__ __forceinline__ void st8a(ushort* p, u64 v) {
  __hip_atomic_store((u64*)p, v, __ATOMIC_RELAXED, __HIP_MEMORY_SCOPE_AGENT);
}

// ---- Hybrid-coherence barrier, 128 WGs, direct poll (R20 + inv-only wait) ----
// h is published by ATOMIC stores (write-through), so arrival needs NO wbl2:
// __syncthreads drains vmcnt (atomic stores land in L3), then one relaxed
// slot store. Wait: lanes poll all slots in parallel, then INV-ONLY
// (buffer_inv sc0 sc1: drop stale L1/L2 lines; no writeback walk). tid0's
// wave drains vmcnt at the trailing __syncthreads, so the inv completes
// before any h load. SAFETY (R2/R4 hangs): ~114KB LDS -> 1 WG/CU; 128 WGs
// vs 256 CUs = 2x co-residency slack. Keep it so.
__device__ __forceinline__ void ebar_arrive(unsigned* slots, unsigned p) {
  __syncthreads();  // vmcnt drained: all atomic h stores visible in L3
  if (threadIdx.x == 0)
    __hip_atomic_store(slots + blockIdx.x * 32, p, __ATOMIC_RELAXED,
                       __HIP_MEMORY_SCOPE_AGENT);
}
__device__ __forceinline__ void ebar_wait(unsigned* slots, unsigned p) {
  if (threadIdx.x < EWG) {
    while (__hip_atomic_load(slots + threadIdx.x * 32, __ATOMIC_RELAXED,
                             __HIP_MEMORY_SCOPE_AGENT) < p)
      __builtin_amdgcn_s_sleep(1);
  }
  __syncthreads();
  if (threadIdx.x == 0)
    asm volatile("buffer_inv sc0 sc1" ::: "memory");  // inv only (no wbl2)
  __syncthreads();
}

// ======================= PREP: split weights to bf16 hi/lo =======================
__global__ __launch_bounds__(512) void prep_split(
    const float* __restrict__ whh0, const float* __restrict__ wih1,
    const float* __restrict__ whh1) {
  const int i = blockIdx.x * 512 + threadIdx.x;  // grid 2048 -> 1M elements
  float a = whh0[i];
  ushort h = f2bf(a);
  (&Whh0h[0][0])[i] = h;
  (&Whh0l[0][0])[i] = f2bf(a - bf2f(h));
  a = wih1[i];
  h = f2bf(a);
  (&Wih1h[0][0])[i] = h;
  (&Wih1l[0][0])[i] = f2bf(a - bf2f(h));
  a = whh1[i];
  h = f2bf(a);
  (&Whh1h[0][0])[i] = h;
  (&Whh1l[0][0])[i] = f2bf(a - bf2f(h));
}

// swizzled ushort offset within a 16x512 weight plane for (row jl, chunk ck)
__device__ __forceinline__ int wswz(int jl, int ck) {
  return jl * 512 + (((ck & 56) | ((ck ^ jl) & 7)) << 3);
}

#define GST 20  // gate-exchange row stride (floats); 80B = 16B-aligned

// ======================= ENCODER (persistent, split-bf16 MFMA; R17 body) =======
__global__ __launch_bounds__(ETH, 2) void enc_kernel(
    const float* __restrict__ x, const float* __restrict__ init_input,
    const float* __restrict__ w_ih0, const float* __restrict__ b0,
    const float* __restrict__ b1, unsigned* ws) {
  const int wg = blockIdx.x;
  const int tid = threadIdx.x;
  const int hcol0 = wg * 4;
  unsigned* eslots = ws;               // 128 slots x 32 stride
  unsigned* wsI = ws + 4096;

  __shared__ __align__(16) ushort sW[6][16 * 512];  // [mat*2+half]
  __shared__ float s_gb0[64 * GST];   // [b][hl*4+gate] (stride-padded)
  __shared__ float s_gb1a[64 * GST];
  __shared__ float s_gb1b[64 * GST];
  __shared__ float s_wih0[16], s_b0[16], s_b1[16];

  // ---- load resident weight slices (once): 6 planes x 1024 chunks ----
  for (int i = tid; i < 6 * 1024; i += ETH) {
    const int plane = i >> 10, c = i & 1023;
    const int row = c >> 6, ck = c & 63;
    const int jsrc = (row >> 2) * HH + hcol0 + (row & 3);
    const ushort* src;
    switch (plane) {
      case 0: src = &Whh0h[0][0]; break;
      case 1: src = &Whh0l[0][0]; break;
      case 2: src = &Wih1h[0][0]; break;
      case 3: src = &Wih1l[0][0]; break;
      case 4: src = &Whh1h[0][0]; break;
      default: src = &Whh1l[0][0]; break;
    }
    *(ushort8*)&sW[plane][wswz(row, ck)] =
        *(const ushort8*)&src[jsrc * HH + ck * 8];
  }
  if (tid < 16) {  // jl = gate*4 + hl
    const int jsrc = (tid >> 2) * HH + hcol0 + (tid & 3);
    s_wih0[tid] = w_ih0[jsrc];
    s_b0[tid] = b0[jsrc];
    s_b1[tid] = b1[jsrc];
  }
  {  // zero-init h state via ATOMIC stores (write-through; no fence needed)
    const int gid = wg * ETH + tid;  // 65536 threads; 16384 u64 quads/array
    if (gid < 16384) {
      st8a(&(&Eh0h[0][0][0])[gid * 4], 0ull);
      st8a(&(&Eh0l[0][0][0])[gid * 4], 0ull);
      st8a(&(&Eh1h[0][0][0])[gid * 4], 0ull);
      st8a(&(&Eh1l[0][0][0])[gid * 4], 0ull);
    }
    if (tid < 256) {  // own c slice (4 hcols x 64 b): self-write-self-read
      const int b = tid >> 2, hc = hcol0 + (tid & 3);
      g_c0[b][hc] = 0.f;
      g_c1[b][hc] = 0.f;
    }
  }
  ebar_arrive(wsI, 1);
  ebar_wait(wsI, 1);

  const int lane = tid & 63, wv = tid >> 6;
  const int grp = wv >> 2;      // 0: h0 -> acc0+acc1a; 1: h1 -> acc1b
  const int mh = wv & 3;        // m-tile: batch rows mh*16..+15
  const int mr = lane & 15, kg = lane >> 4;
  const int arow = mh * 16 + mr;
  // cell indices
  const int cb = tid >> 2, chl = tid & 3;
  const int chcol = hcol0 + chl;

  unsigned p = 1;
  for (int tk = 1; tk <= TT + 1; ++tk) {
    const int cur = (tk - 1) & 1, nxt = tk & 1;
    const bool do0 = (tk <= TT), do1 = (tk >= 2);

    f32x4 acc0 = {0.f, 0.f, 0.f, 0.f};
    f32x4 acc1 = {0.f, 0.f, 0.f, 0.f};
    bf16x8 abuf[16];

    if (grp == 0) {
      const ushort* __restrict__ hrow = &Eh0h[cur][arow][0];
      // ---- pass 1: hi fragments, bulk load then MFMA ----
#pragma unroll
      for (int i = 0; i < 16; ++i)
        abuf[i] = *(const bf16x8*)&hrow[(i >> 1) * 64 + (i & 1) * 32 + kg * 8];
#pragma unroll
      for (int i = 0; i < 16; ++i) {
        const int ck = (i >> 1) * 8 + (i & 1) * 4 + kg;
        if (do0) {
          const bf16x8 bh = *(const bf16x8*)&sW[0][wswz(mr, ck)];
          const bf16x8 bl = *(const bf16x8*)&sW[1][wswz(mr, ck)];
          acc0 = __builtin_amdgcn_mfma_f32_16x16x32_bf16(abuf[i], bh, acc0, 0, 0, 0);
          acc0 = __builtin_amdgcn_mfma_f32_16x16x32_bf16(abuf[i], bl, acc0, 0, 0, 0);
        }
        if (do1) {
          const bf16x8 bh = *(const bf16x8*)&sW[2][wswz(mr, ck)];
          const bf16x8 bl = *(const bf16x8*)&sW[3][wswz(mr, ck)];
          acc1 = __builtin_amdgcn_mfma_f32_16x16x32_bf16(abuf[i], bh, acc1, 0, 0, 0);
          acc1 = __builtin_amdgcn_mfma_f32_16x16x32_bf16(abuf[i], bl, acc1, 0, 0, 0);
        }
      }
      // ---- pass 2: lo fragments x hi weights ----
      const ushort* __restrict__ lrow = &Eh0l[cur][arow][0];
#pragma unroll
      for (int i = 0; i < 16; ++i)
        abuf[i] = *(const bf16x8*)&lrow[(i >> 1) * 64 + (i & 1) * 32 + kg * 8];
#pragma unroll
      for (int i = 0; i < 16; ++i) {
        const int ck = (i >> 1) * 8 + (i & 1) * 4 + kg;
        if (do0) {
          const bf16x8 bh = *(const bf16x8*)&sW[0][wswz(mr, ck)];
          acc0 = __builtin_amdgcn_mfma_f32_16x16x32_bf16(abuf[i], bh, acc0, 0, 0, 0);
        }
        if (do1) {
          const bf16x8 bh = *(const bf16x8*)&sW[2][wswz(mr, ck)];
          acc1 = __builtin_amdgcn_mfma_f32_16x16x32_bf16(abuf[i], bh, acc1, 0, 0, 0);
        }
      }
    } else if (do1) {
      const ushort* __restrict__ hrow = &Eh1h[nxt][arow][0];
#pragma unroll
      for (int i = 0; i < 16; ++i)
        abuf[i] = *(const bf16x8*)&hrow[(i >> 1) * 64 + (i & 1) * 32 + kg * 8];
#pragma unroll
      for (int i = 0; i < 16; ++i) {
        const int ck = (i >> 1) * 8 + (i & 1) * 4 + kg;
        const bf16x8 bh = *(const bf16x8*)&sW[4][wswz(mr, ck)];
        const bf16x8 bl = *(const bf16x8*)&sW[5][wswz(mr, ck)];
        acc1 = __builtin_amdgcn_mfma_f32_16x16x32_bf16(abuf[i], bh, acc1, 0, 0, 0);
        acc1 = __builtin_amdgcn_mfma_f32_16x16x32_bf16(abuf[i], bl, acc1, 0, 0, 0);
      }
      const ushort* __restrict__ lrow = &Eh1l[nxt][arow][0];
#pragma unroll
      for (int i = 0; i < 16; ++i)
        abuf[i] = *(const bf16x8*)&lrow[(i >> 1) * 64 + (i & 1) * 32 + kg * 8];
#pragma unroll
      for (int i = 0; i < 16; ++i) {
        const int ck = (i >> 1) * 8 + (i & 1) * 4 + kg;
        const bf16x8 bh = *(const bf16x8*)&sW[4][wswz(mr, ck)];
        acc1 = __builtin_amdgcn_mfma_f32_16x16x32_bf16(abuf[i], bh, acc1, 0, 0, 0);
      }
    }

    // ---- gate exchange: C row (batch) = mh*16 + kg*4 + r, col jl = mr ----
    {
      const int slot = (mr & 3) * 4 + (mr >> 2);  // [hl][gate]
#pragma unroll
      for (int r = 0; r < 4; ++r) {
        const int b = mh * 16 + kg * 4 + r;
        if (grp == 0) {
          if (do0) s_gb0[b * GST + slot] = acc0[r];
          if (do1) s_gb1a[b * GST + slot] = acc1[r];
        } else if (do1) {
          s_gb1b[b * GST + slot] = acc1[r];
        }
      }
    }
    __syncthreads();

    // ---- cell updates: thread -> (b = tid>>2, hl = tid&3), tid < 256 ----
    // h written with ATOMIC stores (write-through L3; published by arrive's
    // vmcnt drain, no wbl2 needed).
    if (tid < 256) {
      if (do0) {  // cell0 -> h0^{tk}
        const float xv = x[cb * TT + (tk - 1)];
        const float4 gb = *(const float4*)&s_gb0[cb * GST + chl * 4];
        const float iv = gb.x + xv * s_wih0[chl] + s_b0[chl];
        const float fv = gb.y + xv * s_wih0[4 + chl] + s_b0[4 + chl];
        const float gv = gb.z + xv * s_wih0[8 + chl] + s_b0[8 + chl];
        const float ov = gb.w + xv * s_wih0[12 + chl] + s_b0[12 + chl];
        float c = g_c0[cb][chcol];
        const float h = cellupd(iv, fv, gv, ov, c);
        g_c0[cb][chcol] = c;
        const ushort hh = f2bf(h);
        st2a(&Eh0h[nxt][cb][chcol], hh);
        st2a(&Eh0l[nxt][cb][chcol], f2bf(h - bf2f(hh)));
      }
      if (do1) {  // cell1 -> h1^{tk-1}
        const float4 ga = *(const float4*)&s_gb1a[cb * GST + chl * 4];
        const float4 gbb = *(const float4*)&s_gb1b[cb * GST + chl * 4];
        const float iv = ga.x + gbb.x + s_b1[chl];
        const float fv = ga.y + gbb.y + s_b1[4 + chl];
        const float gv = ga.z + gbb.z + s_b1[8 + chl];
        const float ov = ga.w + gbb.w + s_b1[12 + chl];
        float c = g_c1[cb][chcol];
        const float h = cellupd(iv, fv, gv, ov, c);
        g_c1[cb][chcol] = c;
        const ushort hh = f2bf(h);
        st2a(&Eh1h[cur][cb][chcol], hh);
        st2a(&Eh1l[cur][cb][chcol], f2bf(h - bf2f(hh)));
      }
    }
    ebar_arrive(eslots, ++p);
    ebar_wait(eslots, p);
  }

  // ---- expand final states over n_samples: row r = b*16+s ----
  // (last ebar_wait's inv makes peers' final h visible to normal loads)
  {
    {  // ushort8 slots: RR*HH/8 = 65536 == grid threads
      const int idx = wg * ETH + tid;
      const int r = idx >> 6, k8 = (idx & 63) * 8, b = r >> 4;
      *(ushort8*)&H0h[0][r][k8] = *(const ushort8*)&Eh0h[0][b][k8];
      *(ushort8*)&H0l[0][r][k8] = *(const ushort8*)&Eh0l[0][b][k8];
      *(ushort8*)&H1h[0][r][k8] = *(const ushort8*)&Eh1h[0][b][k8];
      *(ushort8*)&H1l[0][r][k8] = *(const ushort8*)&Eh1l[0][b][k8];
    }
    // C expansion: OWN hcols only (c is local to this WG)
    for (int i = tid; i < RR * 4; i += ETH) {
      const int r = i >> 2, hc = hcol0 + (i & 3), b = r >> 4;
      g_C0[r][hc] = g_c0[b][hc];
      g_C1[r][hc] = g_c1[b][hc];
    }
    const int gid = wg * ETH + tid;
    if (gid < RR) g_u[0][gid] = init_input[gid];
  }
}

// ======================= DECODER (per-step, reg-staged pipelined; R19) =========
__global__ __launch_bounds__(512, 4) void dec_l0(
    const float* __restrict__ w_ih0, const float* __restrict__ b0,
    const float* __restrict__ b_out, float* __restrict__ out, int d) {
  __shared__ __align__(16) ushort Ah[64][72], Al[64][72];
  __shared__ __align__(16) ushort Bh[128][72], Bl[128][72];
  __shared__ float s_wi[128], s_bi[128];
  const int tid = threadIdx.x;
  const int CG = blockIdx.x & 15, RQ = blockIdx.x >> 4;
  const int row0 = RQ * 64, hcol0 = CG * 32;
  const int lane = tid & 63, wv = tid >> 6;
  const int wm = wv & 3, wn = wv >> 2;
  const int mr = lane & 15, kg = lane >> 4;

  if (tid < 128) {
    const int jsrc = (tid >> 5) * HH + hcol0 + (tid & 31);
    s_wi[tid] = w_ih0[jsrc];
    s_bi[tid] = b0[jsrc];
  }

  const int cur = d & 1, nxt = cur ^ 1;
  const ushort* __restrict__ Ahg = &H0h[cur][0][0];
  const ushort* __restrict__ Alg = &H0l[cur][0][0];

  const int mA = tid >> 3, kkA = (tid & 7) * 8;
  const int j2a = tid >> 3, j2b = 64 + (tid >> 3);
  const int aoff = (row0 + mA) * HH + kkA;
  const int b0off = ((j2a >> 5) * HH + hcol0 + (j2a & 31)) * HH + kkA;
  const int b1off = ((j2b >> 5) * HH + hcol0 + (j2b & 31)) * HH + kkA;
  const ushort* __restrict__ WBh = &Whh0h[0][0];
  const ushort* __restrict__ WBl = &Whh0l[0][0];

  f32x4 acc[4];
#pragma unroll
  for (int g = 0; g < 4; ++g) acc[g] = (f32x4){0.f, 0.f, 0.f, 0.f};

  bf16x8 rAh = *(const bf16x8*)&Ahg[aoff];
  bf16x8 rAl = *(const bf16x8*)&Alg[aoff];
  bf16x8 rB0h = *(const bf16x8*)&WBh[b0off];
  bf16x8 rB0l = *(const bf16x8*)&WBl[b0off];
  bf16x8 rB1h = *(const bf16x8*)&WBh[b1off];
  bf16x8 rB1l = *(const bf16x8*)&WBl[b1off];

  for (int kt = 0; kt < 8; ++kt) {
    __syncthreads();
    *(bf16x8*)&Ah[mA][kkA] = rAh;
    *(bf16x8*)&Al[mA][kkA] = rAl;
    *(bf16x8*)&Bh[j2a][kkA] = rB0h;
    *(bf16x8*)&Bl[j2a][kkA] = rB0l;
    *(bf16x8*)&Bh[j2b][kkA] = rB1h;
    *(bf16x8*)&Bl[j2b][kkA] = rB1l;
    __syncthreads();
    if (kt < 7) {
      const int k0n = (kt + 1) * 64;
      rAh = *(const bf16x8*)&Ahg[aoff + k0n];
      rAl = *(const bf16x8*)&Alg[aoff + k0n];
      rB0h = *(const bf16x8*)&WBh[b0off + k0n];
      rB0l = *(const bf16x8*)&WBl[b0off + k0n];
      rB1h = *(const bf16x8*)&WBh[b1off + k0n];
      rB1l = *(const bf16x8*)&WBl[b1off + k0n];
    }
#pragma unroll
    for (int ks2 = 0; ks2 < 2; ++ks2) {
      const int ko = ks2 * 32 + kg * 8;
      const bf16x8 ah = *(const bf16x8*)&Ah[wm * 16 + mr][ko];
      const bf16x8 al = *(const bf16x8*)&Al[wm * 16 + mr][ko];
#pragma unroll
      for (int g = 0; g < 4; ++g) {
        const bf16x8 bh = *(const bf16x8*)&Bh[g * 32 + wn * 16 + mr][ko];
        const bf16x8 bl = *(const bf16x8*)&Bl[g * 32 + wn * 16 + mr][ko];
        acc[g] = __builtin_amdgcn_mfma_f32_16x16x32_bf16(ah, bh, acc[g], 0, 0, 0);
        acc[g] = __builtin_amdgcn_mfma_f32_16x16x32_bf16(ah, bl, acc[g], 0, 0, 0);
        acc[g] = __builtin_amdgcn_mfma_f32_16x16x32_bf16(al, bh, acc[g], 0, 0, 0);
      }
    }
  }

  const int hl2 = wn * 16 + mr;
  const int hcol = hcol0 + hl2;
  const int ub = d & 1, nb = ub ^ 1;
  const float bo = b_out[0];
#pragma unroll
  for (int r = 0; r < 4; ++r) {
    const int row = row0 + wm * 16 + kg * 4 + r;
    const float u = g_u[ub][row];
    const float iv = acc[0][r] + u * s_wi[hl2] + s_bi[hl2];
    const float fv = acc[1][r] + u * s_wi[32 + hl2] + s_bi[32 + hl2];
    const float gv = acc[2][r] + u * s_wi[64 + hl2] + s_bi[64 + hl2];
    const float ov = acc[3][r] + u * s_wi[96 + hl2] + s_bi[96 + hl2];
    float c = g_C0[row][hcol];
    const float h = cellupd(iv, fv, gv, ov, c);
    g_C0[row][hcol] = c;
    const ushort hh = f2bf(h);
    H0h[nxt][row][hcol] = hh;
    H0l[nxt][row][hcol] = f2bf(h - bf2f(hh));
    if (CG == 0 && wn == 0 && mr == 0) {
      g_u[nb][row] = bo;
      out[row * HOR + d] = bo;
    }
  }
}

__global__ __launch_bounds__(512, 4) void dec_l1(
    const float* __restrict__ b1, const float* __restrict__ w_out,
    float* __restrict__ out, int d) {
  __shared__ __align__(16) ushort Ah[64][72], Al[64][72];
  __shared__ __align__(16) ushort Bh[128][72], Bl[128][72];
  __shared__ float s_bi[128];
  const int tid = threadIdx.x;
  const int CG = blockIdx.x & 15, RQ = blockIdx.x >> 4;
  const int row0 = RQ * 64, hcol0 = CG * 32;
  const int lane = tid & 63, wv = tid >> 6;
  const int wm = wv & 3, wn = wv >> 2;
  const int mr = lane & 15, kg = lane >> 4;

  if (tid < 128) {
    const int jsrc = (tid >> 5) * HH + hcol0 + (tid & 31);
    s_bi[tid] = b1[jsrc];
  }

  const int cur = d & 1, nxt = cur ^ 1;

  const int mA = tid >> 3, kkA = (tid & 7) * 8;
  const int j2a = tid >> 3, j2b = 64 + (tid >> 3);
  const int aoff = (row0 + mA) * HH + kkA;
  const int b0off = ((j2a >> 5) * HH + hcol0 + (j2a & 31)) * HH + kkA;
  const int b1off = ((j2b >> 5) * HH + hcol0 + (j2b & 31)) * HH + kkA;

  f32x4 acc[4];
#pragma unroll
  for (int g = 0; g < 4; ++g) acc[g] = (f32x4){0.f, 0.f, 0.f, 0.f};

#pragma unroll
  for (int src = 0; src < 2; ++src) {
    const ushort* __restrict__ Ahg = src ? &H1h[cur][0][0] : &H0h[nxt][0][0];
    const ushort* __restrict__ Alg = src ? &H1l[cur][0][0] : &H0l[nxt][0][0];
    const ushort* __restrict__ WBh = src ? &Whh1h[0][0] : &Wih1h[0][0];
    const ushort* __restrict__ WBl = src ? &Whh1l[0][0] : &Wih1l[0][0];

    bf16x8 rAh = *(const bf16x8*)&Ahg[aoff];
    bf16x8 rAl = *(const bf16x8*)&Alg[aoff];
    bf16x8 rB0h = *(const bf16x8*)&WBh[b0off];
    bf16x8 rB0l = *(const bf16x8*)&WBl[b0off];
    bf16x8 rB1h = *(const bf16x8*)&WBh[b1off];
    bf16x8 rB1l = *(const bf16x8*)&WBl[b1off];

    for (int kt = 0; kt < 8; ++kt) {
      __syncthreads();
      *(bf16x8*)&Ah[mA][kkA] = rAh;
      *(bf16x8*)&Al[mA][kkA] = rAl;
      *(bf16x8*)&Bh[j2a][kkA] = rB0h;
      *(bf16x8*)&Bl[j2a][kkA] = rB0l;
      *(bf16x8*)&Bh[j2b][kkA] = rB1h;
      *(bf16x8*)&Bl[j2b][kkA] = rB1l;
      __syncthreads();
      if (kt < 7) {
        const int k0n = (kt + 1) * 64;
        rAh = *(const bf16x8*)&Ahg[aoff + k0n];
        rAl = *(const bf16x8*)&Alg[aoff + k0n];
        rB0h = *(const bf16x8*)&WBh[b0off + k0n];
        rB0l = *(const bf16x8*)&WBl[b0off + k0n];
        rB1h = *(const bf16x8*)&WBh[b1off + k0n];
        rB1l = *(const bf16x8*)&WBl[b1off + k0n];
      }
#pragma unroll
      for (int ks2 = 0; ks2 < 2; ++ks2) {
        const int ko = ks2 * 32 + kg * 8;
        const bf16x8 ah = *(const bf16x8*)&Ah[wm * 16 + mr][ko];
        const bf16x8 al = *(const bf16x8*)&Al[wm * 16 + mr][ko];
#pragma unroll
        for (int g = 0; g < 4; ++g) {
          const bf16x8 bh = *(const bf16x8*)&Bh[g * 32 + wn * 16 + mr][ko];
          const bf16x8 bl = *(const bf16x8*)&Bl[g * 32 + wn * 16 + mr][ko];
          acc[g] = __builtin_amdgcn_mfma_f32_16x16x32_bf16(ah, bh, acc[g], 0, 0, 0);
          acc[g] = __builtin_amdgcn_mfma_f32_16x16x32_bf16(ah, bl, acc[g], 0, 0, 0);
          acc[g] = __builtin_amdgcn_mfma_f32_16x16x32_bf16(al, bh, acc[g], 0, 0, 0);
        }
      }
    }
  }

  const int hl2 = wn * 16 + mr;
  const int hcol = hcol0 + hl2;
  const int nb = (d & 1) ^ 1;
  const float wo = w_out[hcol];
  float pp[4];
#pragma unroll
  for (int r = 0; r < 4; ++r) {
    const int row = row0 + wm * 16 + kg * 4 + r;
    const float iv = acc[0][r] + s_bi[hl2];
    const float fv = acc[1][r] + s_bi[32 + hl2];
    const float gv = acc[2][r] + s_bi[64 + hl2];
    const float ov = acc[3][r] + s_bi[96 + hl2];
    float c = g_C1[row][hcol];
    const float h = cellupd(iv, fv, gv, ov, c);
    g_C1[row][hcol] = c;
    const ushort hh = f2bf(h);
    H1h[nxt][row][hcol] = hh;
    H1l[nxt][row][hcol] = f2bf(h - bf2f(hh));
    pp[r] = h * wo;
  }
#pragma unroll
  for (int off = 1; off < 16; off <<= 1) {
#pragma unroll
    for (int r = 0; r < 4; ++r) pp[r] += __shfl_xor(pp[r], off);
  }
  if (mr == 0) {
#pragma unroll
    for (int r = 0; r < 4; ++r) {
      const int row = row0 + wm * 16 + kg * 4 + r;
      atomicAdd(&g_u[nb][row], pp[r]);
      atomicAdd(&out[row * HOR + d], pp[r]);
    }
  }
}

extern "C" void kernel_launch(void* const* d_in, const int* in_sizes, int n_in,
                              void* d_out, int out_size, void* d_ws, size_t ws_size,
                              hipStream_t stream) {
  (void)in_sizes; (void)n_in; (void)out_size; (void)ws_size;
  const float* x = (const float*)d_in[0];
  const float* init_input = (const float*)d_in[1];
  const float* w_ih0 = (const float*)d_in[2];
  const float* w_hh0 = (const float*)d_in[3];
  const float* b0 = (const float*)d_in[4];
  const float* w_ih1 = (const float*)d_in[5];
  const float* w_hh1 = (const float*)d_in[6];
  const float* b1 = (const float*)d_in[7];
  const float* w_out = (const float*)d_in[8];
  const float* b_out = (const float*)d_in[9];
  float* out = (float*)d_out;

  hipMemsetAsync(d_ws, 0, 8192 * sizeof(unsigned), stream);
  prep_split<<<2048, 512, 0, stream>>>(w_hh0, w_ih1, w_hh1);
  enc_kernel<<<EWG, ETH, 0, stream>>>(x, init_input, w_ih0, b0, b1,
                                      (unsigned*)d_ws);
  for (int d = 0; d < HOR; ++d) {
    dec_l0<<<256, 512, 0, stream>>>(w_ih0, b0, b_out, out, d);
    dec_l1<<<256, 512, 0, stream>>>(b1, w_out, out, d);
  }
}